// Round 12
// baseline (175.861 us; speedup 1.0000x reference)
//
#include <hip/hip_runtime.h>
#include <hip/hip_bf16.h>

// CrossNATBlock2D: B=1, H=W=128, C=128, HEADS=4, HD=32, K=7  (fp32 I/O)
// R12: ILP attack. All GEMM loops have compile-time trips + full unroll,
// A-fragments preloaded to registers (invariant across jt), 2-way accumulator
// interleave (shared A, two B streams) in proj/fc1/fc2. Structure = R11.

#define N_PIX 16384
#define C 128
#define HEADS 4
#define HD 32
#define HW 128

typedef __hip_bfloat16 bf16;
typedef __attribute__((ext_vector_type(8))) short bf16x8;
typedef __attribute__((ext_vector_type(4))) float f32x4;

__device__ __forceinline__ short f2bs(float f) {
    bf16 h = __float2bfloat16(f);
    return (short)__bfloat16_as_ushort(h);
}
__device__ __forceinline__ float bs2f(short s) {
    __hip_bfloat16_raw r; r.x = (unsigned short)s;
    return __bfloat162float(__hip_bfloat16(r));
}
__device__ __forceinline__ float gelu_f(float v) {
    const float z = 1.5957691216f * (v + 0.044715f * v * v * v);
    return v / (1.f + __expf(-z));
}

// ---------- kernel 0: convert weights fp32 -> bf16 into ws ----------
__global__ __launch_bounds__(256) void k_wconv(
    const float* __restrict__ qv_w, const float* __restrict__ k_w,
    const float* __restrict__ proj_w, const float* __restrict__ fc1_w,
    const float* __restrict__ fc2_w,
    short* __restrict__ wqv, short* __restrict__ wk, short* __restrict__ wproj,
    short* __restrict__ wfc1, short* __restrict__ wfc2) {
    const int i = blockIdx.x * 256 + threadIdx.x;
    if (i < 32768) wqv[i] = f2bs(qv_w[i]);
    if (i < 16384) { wk[i] = f2bs(k_w[i]); wproj[i] = f2bs(proj_w[i]); }
    if (i < 65536) { wfc1[i] = f2bs(fc1_w[i]); wfc2[i] = f2bs(fc2_w[i]); }
}

// ---------- kernel 1: LN1 + QV GEMM + K proj, 32 px/block, 512 thr ----------
__global__ __launch_bounds__(512, 6) void k_qkv(
    const float* __restrict__ x, const float* __restrict__ y,
    const short* __restrict__ wqv, const float* __restrict__ qv_b,
    const short* __restrict__ wk, const float* __restrict__ k_b,
    const float* __restrict__ n1_w, const float* __restrict__ n1_b,
    bf16* __restrict__ qb, bf16* __restrict__ vb, bf16* __restrict__ kb) {
    __shared__ float xr[32][132];
    __shared__ short xn[32][136];
    __shared__ short yb[32][136];
    __shared__ float muA[32], riA[32];
    const int t = threadIdx.x;
    const int pix0 = blockIdx.x * 32;
    for (int e = t; e < 32 * 128; e += 512) {
        const int r = e >> 7, c = e & 127;
        xr[r][c] = x[(pix0 + r) * C + c];
        yb[r][c] = f2bs(y[(pix0 + r) * C + c]);
    }
    __syncthreads();
    if (t < 256) {
        const int r = t >> 3, s = t & 7;
        float sm = 0.f, sq = 0.f;
        for (int i = 0; i < 16; i++) { float v = xr[r][s * 16 + i]; sm += v; sq += v * v; }
        for (int m = 1; m < 8; m <<= 1) { sm += __shfl_xor(sm, m, 64); sq += __shfl_xor(sq, m, 64); }
        if (s == 0) {
            const float mu = sm * (1.f / 128.f);
            const float var = sq * (1.f / 128.f) - mu * mu;
            muA[r] = mu; riA[r] = rsqrtf(var + 1e-5f);
        }
    }
    __syncthreads();
    for (int e = t; e < 32 * 128; e += 512) {
        const int r = e >> 7, c = e & 127;
        xn[r][c] = f2bs((xr[r][c] - muA[r]) * riA[r] * n1_w[c] + n1_b[c]);
    }
    __syncthreads();
    const int wave = t >> 6, lane = t & 63, quad = lane >> 4, l15 = lane & 15;
    const int mt = wave & 1, wv = wave >> 1;   // fixed A-row-set per wave
    const float scale = 0.1767766952966369f;   // 1/sqrt(32)
    // ---- qv GEMM: A preloaded once, 4 unrolled n-tiles ----
    {
        bf16x8 aA[4];
#pragma unroll
        for (int kt = 0; kt < 4; kt++)
            aA[kt] = *(const bf16x8*)&xn[mt * 16 + l15][kt * 32 + quad * 8];
#pragma unroll
        for (int s = 0; s < 4; s++) {
            const int n = (wv * 4 + s) * 16 + l15;
            f32x4 acc = {0.f, 0.f, 0.f, 0.f};
#pragma unroll
            for (int kt = 0; kt < 4; kt++) {
                bf16x8 b = *(const bf16x8*)&wqv[n * C + kt * 32 + quad * 8];
                acc = __builtin_amdgcn_mfma_f32_16x16x32_bf16(aA[kt], b, acc, 0, 0, 0);
            }
            const float bias = qv_b[n];
#pragma unroll
            for (int r = 0; r < 4; r++) {
                const int m = mt * 16 + quad * 4 + r;
                const float v = acc[r] + bias;
                if (n < C) qb[(pix0 + m) * C + n] = __float2bfloat16(v * scale);
                else       vb[(pix0 + m) * C + (n - C)] = __float2bfloat16(v);
            }
        }
    }
    // ---- k GEMM: A preloaded, 2 unrolled n-tiles (interleaved accs) ----
    {
        bf16x8 aY[4];
#pragma unroll
        for (int kt = 0; kt < 4; kt++)
            aY[kt] = *(const bf16x8*)&yb[mt * 16 + l15][kt * 32 + quad * 8];
        const int n0 = (wv * 2) * 16 + l15, n1 = (wv * 2 + 1) * 16 + l15;
        f32x4 a0 = {0.f, 0.f, 0.f, 0.f}, a1 = {0.f, 0.f, 0.f, 0.f};
#pragma unroll
        for (int kt = 0; kt < 4; kt++) {
            bf16x8 b0 = *(const bf16x8*)&wk[n0 * C + kt * 32 + quad * 8];
            bf16x8 b1 = *(const bf16x8*)&wk[n1 * C + kt * 32 + quad * 8];
            a0 = __builtin_amdgcn_mfma_f32_16x16x32_bf16(aY[kt], b0, a0, 0, 0, 0);
            a1 = __builtin_amdgcn_mfma_f32_16x16x32_bf16(aY[kt], b1, a1, 0, 0, 0);
        }
        const float b0s = k_b[n0], b1s = k_b[n1];
#pragma unroll
        for (int r = 0; r < 4; r++) {
            const int m = mt * 16 + quad * 4 + r;
            kb[(pix0 + m) * C + n0] = __float2bfloat16(a0[r] + b0s);
            kb[(pix0 + m) * C + n1] = __float2bfloat16(a1[r] + b1s);
        }
    }
}

// ---------- kernel 2: fused attention + proj + residual + LN2 + MLP ----------
__global__ __launch_bounds__(256) void k_fam(
    const bf16* __restrict__ qb, const bf16* __restrict__ kb,
    const bf16* __restrict__ vb, const float* __restrict__ rpb,
    const float* __restrict__ x,
    const short* __restrict__ wproj, const float* __restrict__ proj_b,
    const float* __restrict__ n2_w, const float* __restrict__ n2_b,
    const short* __restrict__ wfc1, const float* __restrict__ fc1_b,
    const short* __restrict__ wfc2, const float* __restrict__ fc2_b,
    float* __restrict__ out) {
    __shared__ short KP[13200];
    __shared__ short Vl[13200];
    __shared__ float muA[16], riA[16];
    short* const Pm  = KP;            // 64 x 136
    short* const aoL = KP + 8704;     // 16 x 136
    short* const x1b = KP + 10880;    // 16 x 136
    short* const hb  = Vl;            // 16 x 520
    short* const xnb = Vl + 8320;     // 16 x 136
    const int t = threadIdx.x;
    const int h = t >> 6, lane = t & 63, quad = lane >> 4, l15 = lane & 15;
    const int i0 = (blockIdx.x >> 5) * 4;
    const int j0 = (blockIdx.x & 31) * 4;
    const int rs = min(max(i0 - 3, 0), 118);
    const int cs = min(max(j0 - 3, 0), 118);
    // ---- phase 1: stage K,V unions ----
    for (int u = t; u < 100 * 16 * 2; u += 256) {
        const int tv = (u >= 1600) ? 1 : 0;
        const int uu = tv ? u - 1600 : u;
        const int r = uu >> 4, seg = uu & 15;
        const size_t g = (size_t)((rs + r / 10) * HW + cs + r % 10) * C + seg * 8;
        const uint4 d = *(const uint4*)((tv ? vb : kb) + g);
        *(uint4*)&(tv ? Vl : KP)[r * 132 + seg * 8] = d;
    }
    __syncthreads();
    // ---- phase 2: QK^T + bias/mask + softmax (wave = head) ----
    const int pA = (i0 + (l15 >> 2)) * HW + j0 + (l15 & 3);
    const bf16x8 aQ = *(const bf16x8*)(qb + (size_t)pA * C + h * HD + quad * 8);
    f32x4 S[7];
    int aiL[7], ajL[7]; bool inb[7];
#pragma unroll
    for (int nt = 0; nt < 7; nt++) {
        const int nb = nt * 16 + l15;
        aiL[nt] = rs + nb / 10;
        ajL[nt] = cs + nb % 10;
        inb[nt] = nb < 100;
        const bf16x8 bK = *(const bf16x8*)&KP[(nt * 16 + l15) * 132 + h * HD + quad * 8];
        f32x4 z = {0.f, 0.f, 0.f, 0.f};
        S[nt] = __builtin_amdgcn_mfma_f32_16x16x32_bf16(aQ, bK, z, 0, 0, 0);
    }
    const float* rpbh = rpb + h * 169;
    float smx[4];
#pragma unroll
    for (int r = 0; r < 4; r++) {
        const int m = quad * 4 + r;
        const int i = i0 + (m >> 2), j = j0 + (m & 3);
        const int shi = min(max(i - 3, 0), 121);
        const int swj = min(max(j - 3, 0), 121);
        float best = -1e30f;
#pragma unroll
        for (int nt = 0; nt < 7; nt++) {
            const int ai = aiL[nt], aj = ajL[nt];
            const bool valid = inb[nt] & (ai >= shi) & (ai <= shi + 6) & (aj >= swj) & (aj <= swj + 6);
            const int ri = min(max(ai - i + 6, 0), 12);
            const int rj = min(max(aj - j + 6, 0), 12);
            const float v = valid ? (S[nt][r] + rpbh[ri * 13 + rj]) : -1e30f;
            S[nt][r] = v;
            best = fmaxf(best, v);
        }
        for (int msk = 1; msk < 16; msk <<= 1) best = fmaxf(best, __shfl_xor(best, msk, 64));
        float s = 0.f;
#pragma unroll
        for (int nt = 0; nt < 7; nt++) {
            const float e = __expf(S[nt][r] - best);
            S[nt][r] = e;
            s += e;
        }
        for (int msk = 1; msk < 16; msk <<= 1) s += __shfl_xor(s, msk, 64);
        smx[r] = 1.f / s;
    }
    __syncthreads();
    // ---- phase 3: P -> Pm ----
#pragma unroll
    for (int r = 0; r < 4; r++) {
        short* prow = &Pm[(h * 16 + quad * 4 + r) * 136];
#pragma unroll
        for (int nt = 0; nt < 7; nt++)
            prow[nt * 16 + l15] = f2bs(S[nt][r] * smx[r]);
        prow[112 + l15] = 0;
    }
    __syncthreads();
    // ---- phase 4: PV -> aoL ----
    f32x4 O0 = {0.f, 0.f, 0.f, 0.f}, O1 = {0.f, 0.f, 0.f, 0.f};
#pragma unroll
    for (int kt = 0; kt < 4; kt++) {
        const bf16x8 aP = *(const bf16x8*)&Pm[(h * 16 + l15) * 136 + kt * 32 + quad * 8];
#pragma unroll
        for (int nt2 = 0; nt2 < 2; nt2++) {
            bf16x8 bV;
            const int ch = h * HD + nt2 * 16 + l15;
#pragma unroll
            for (int jj = 0; jj < 8; jj++) {
                const int nbr = kt * 32 + quad * 8 + jj;
                bV[jj] = (nbr < 100) ? Vl[nbr * 132 + ch] : (short)0;
            }
            if (nt2 == 0) O0 = __builtin_amdgcn_mfma_f32_16x16x32_bf16(aP, bV, O0, 0, 0, 0);
            else          O1 = __builtin_amdgcn_mfma_f32_16x16x32_bf16(aP, bV, O1, 0, 0, 0);
        }
    }
#pragma unroll
    for (int r = 0; r < 4; r++) {
        const int m = quad * 4 + r;
        aoL[m * 136 + h * HD + l15] = f2bs(O0[r]);
        aoL[m * 136 + h * HD + 16 + l15] = f2bs(O1[r]);
    }
    __syncthreads();
    // ---- phase 5: proj + residual -> x1b (A preloaded, 2-way interleave) ----
    {
        bf16x8 aO[4];
#pragma unroll
        for (int kt = 0; kt < 4; kt++)
            aO[kt] = *(const bf16x8*)&aoL[l15 * 136 + kt * 32 + quad * 8];
        const int n0 = h * 16 + l15, n1 = (h + 4) * 16 + l15;
        f32x4 a0 = {0.f, 0.f, 0.f, 0.f}, a1 = {0.f, 0.f, 0.f, 0.f};
#pragma unroll
        for (int kt = 0; kt < 4; kt++) {
            bf16x8 b0 = *(const bf16x8*)&wproj[n0 * C + kt * 32 + quad * 8];
            bf16x8 b1 = *(const bf16x8*)&wproj[n1 * C + kt * 32 + quad * 8];
            a0 = __builtin_amdgcn_mfma_f32_16x16x32_bf16(aO[kt], b0, a0, 0, 0, 0);
            a1 = __builtin_amdgcn_mfma_f32_16x16x32_bf16(aO[kt], b1, a1, 0, 0, 0);
        }
        const float b0s = proj_b[n0], b1s = proj_b[n1];
#pragma unroll
        for (int r = 0; r < 4; r++) {
            const int m = quad * 4 + r;
            const int p = (i0 + (m >> 2)) * HW + j0 + (m & 3);
            x1b[m * 136 + n0] = f2bs(x[(size_t)p * C + n0] + a0[r] + b0s);
            x1b[m * 136 + n1] = f2bs(x[(size_t)p * C + n1] + a1[r] + b1s);
        }
    }
    __syncthreads();
    // ---- phase 6: LN2 stats ----
    if (t < 128) {
        const int r = t >> 3, s = t & 7;
        float sm = 0.f, sq = 0.f;
        for (int i = 0; i < 16; i++) { float v = bs2f(x1b[r * 136 + s * 16 + i]); sm += v; sq += v * v; }
        for (int m = 1; m < 8; m <<= 1) { sm += __shfl_xor(sm, m, 64); sq += __shfl_xor(sq, m, 64); }
        if (s == 0) {
            const float mu = sm * (1.f / 128.f);
            const float var = sq * (1.f / 128.f) - mu * mu;
            muA[r] = mu; riA[r] = rsqrtf(var + 1e-5f);
        }
    }
    __syncthreads();
    // ---- phase 7: xn = LN(x1) -> xnb ----
    for (int e = t; e < 16 * 128; e += 256) {
        const int r = e >> 7, c = e & 127;
        xnb[r * 136 + c] = f2bs((bs2f(x1b[r * 136 + c]) - muA[r]) * riA[r] * n2_w[c] + n2_b[c]);
    }
    __syncthreads();
    // ---- phase 8: fc1 + gelu -> hb (A preloaded, 4 x 2-way interleave) ----
    {
        bf16x8 aX[4];
#pragma unroll
        for (int kt = 0; kt < 4; kt++)
            aX[kt] = *(const bf16x8*)&xnb[l15 * 136 + kt * 32 + quad * 8];
#pragma unroll
        for (int a = 0; a < 4; a++) {
            const int n0 = (h + 8 * a) * 16 + l15, n1 = (h + 8 * a + 4) * 16 + l15;
            f32x4 a0 = {0.f, 0.f, 0.f, 0.f}, a1 = {0.f, 0.f, 0.f, 0.f};
#pragma unroll
            for (int kt = 0; kt < 4; kt++) {
                bf16x8 b0 = *(const bf16x8*)&wfc1[n0 * C + kt * 32 + quad * 8];
                bf16x8 b1 = *(const bf16x8*)&wfc1[n1 * C + kt * 32 + quad * 8];
                a0 = __builtin_amdgcn_mfma_f32_16x16x32_bf16(aX[kt], b0, a0, 0, 0, 0);
                a1 = __builtin_amdgcn_mfma_f32_16x16x32_bf16(aX[kt], b1, a1, 0, 0, 0);
            }
            const float b0s = fc1_b[n0], b1s = fc1_b[n1];
#pragma unroll
            for (int r = 0; r < 4; r++) {
                hb[(quad * 4 + r) * 520 + n0] = f2bs(gelu_f(a0[r] + b0s));
                hb[(quad * 4 + r) * 520 + n1] = f2bs(gelu_f(a1[r] + b1s));
            }
        }
    }
    __syncthreads();
    // ---- phase 9: fc2 + residual -> out (2-way interleave, shared A) ----
    {
        const int n0 = h * 16 + l15, n1 = (h + 4) * 16 + l15;
        f32x4 a0 = {0.f, 0.f, 0.f, 0.f}, a1 = {0.f, 0.f, 0.f, 0.f};
#pragma unroll
        for (int kt = 0; kt < 16; kt++) {
            const bf16x8 aP = *(const bf16x8*)&hb[l15 * 520 + kt * 32 + quad * 8];
            bf16x8 b0 = *(const bf16x8*)&wfc2[n0 * 512 + kt * 32 + quad * 8];
            bf16x8 b1 = *(const bf16x8*)&wfc2[n1 * 512 + kt * 32 + quad * 8];
            a0 = __builtin_amdgcn_mfma_f32_16x16x32_bf16(aP, b0, a0, 0, 0, 0);
            a1 = __builtin_amdgcn_mfma_f32_16x16x32_bf16(aP, b1, a1, 0, 0, 0);
        }
        const float b0s = fc2_b[n0], b1s = fc2_b[n1];
#pragma unroll
        for (int r = 0; r < 4; r++) {
            const int m = quad * 4 + r;
            const int p = (i0 + (m >> 2)) * HW + j0 + (m & 3);
            out[(size_t)p * C + n0] = a0[r] + b0s + bs2f(x1b[m * 136 + n0]);
            out[(size_t)p * C + n1] = a1[r] + b1s + bs2f(x1b[m * 136 + n1]);
        }
    }
}

extern "C" void kernel_launch(void* const* d_in, const int* in_sizes, int n_in,
                              void* d_out, int out_size, void* d_ws, size_t ws_size,
                              hipStream_t stream) {
    const float* x      = (const float*)d_in[0];
    const float* y      = (const float*)d_in[1];
    const float* qv_w   = (const float*)d_in[2];
    const float* qv_b   = (const float*)d_in[3];
    const float* k_w    = (const float*)d_in[4];
    const float* k_b    = (const float*)d_in[5];
    const float* rpb    = (const float*)d_in[6];
    const float* proj_w = (const float*)d_in[7];
    const float* proj_b = (const float*)d_in[8];
    const float* n1_w   = (const float*)d_in[9];
    const float* n1_b   = (const float*)d_in[10];
    const float* n2_w   = (const float*)d_in[11];
    const float* n2_b   = (const float*)d_in[12];
    const float* fc1_w  = (const float*)d_in[13];
    const float* fc1_b  = (const float*)d_in[14];
    const float* fc2_w  = (const float*)d_in[15];
    const float* fc2_b  = (const float*)d_in[16];
    float* out = (float*)d_out;

    bf16* qb  = (bf16*)d_ws;
    bf16* vb  = qb + (size_t)N_PIX * C;
    bf16* kb  = vb + (size_t)N_PIX * C;
    short* wqv  = (short*)(kb + (size_t)N_PIX * C); // 32768
    short* wk   = wqv + 32768;                      // 16384
    short* wproj= wk + 16384;                       // 16384
    short* wfc1 = wproj + 16384;                    // 65536
    short* wfc2 = wfc1 + 65536;                     // 65536  (total ~12.4 MB)

    k_wconv<<<256, 256, 0, stream>>>(qv_w, k_w, proj_w, fc1_w, fc2_w,
                                     wqv, wk, wproj, wfc1, wfc2);
    k_qkv<<<N_PIX / 32, 512, 0, stream>>>(x, y, wqv, qv_b, wk, k_b, n1_w, n1_b, qb, vb, kb);
    k_fam<<<1024, 256, 0, stream>>>(qb, kb, vb, rpb, x, wproj, proj_b, n2_w, n2_b,
                                    wfc1, fc1_b, wfc2, fc2_b, out);
}

// Round 13
// 175.502 us; speedup vs baseline: 1.0020x; 1.0020x over previous
//
#include <hip/hip_runtime.h>
#include <hip/hip_bf16.h>

// CrossNATBlock2D: B=1, H=W=128, C=128, HEADS=4, HD=32, K=7  (fp32 I/O)
// R13: R12 + XCD-locality swizzle. Producer (k_qkv) and consumer (k_fam) of
// each 16-image-row band are pinned to the same XCD via blockIdx%8 decode, so
// k_fam's k/v halo staging hits the local 4MB L2 instead of remote-XCD/HBM.

#define N_PIX 16384
#define C 128
#define HEADS 4
#define HD 32
#define HW 128

typedef __hip_bfloat16 bf16;
typedef __attribute__((ext_vector_type(8))) short bf16x8;
typedef __attribute__((ext_vector_type(4))) float f32x4;

__device__ __forceinline__ short f2bs(float f) {
    bf16 h = __float2bfloat16(f);
    return (short)__bfloat16_as_ushort(h);
}
__device__ __forceinline__ float bs2f(short s) {
    __hip_bfloat16_raw r; r.x = (unsigned short)s;
    return __bfloat162float(__hip_bfloat16(r));
}
__device__ __forceinline__ float gelu_f(float v) {
    const float z = 1.5957691216f * (v + 0.044715f * v * v * v);
    return v / (1.f + __expf(-z));
}

// ---------- kernel 0: convert weights fp32 -> bf16 into ws ----------
__global__ __launch_bounds__(256) void k_wconv(
    const float* __restrict__ qv_w, const float* __restrict__ k_w,
    const float* __restrict__ proj_w, const float* __restrict__ fc1_w,
    const float* __restrict__ fc2_w,
    short* __restrict__ wqv, short* __restrict__ wk, short* __restrict__ wproj,
    short* __restrict__ wfc1, short* __restrict__ wfc2) {
    const int i = blockIdx.x * 256 + threadIdx.x;
    if (i < 32768) wqv[i] = f2bs(qv_w[i]);
    if (i < 16384) { wk[i] = f2bs(k_w[i]); wproj[i] = f2bs(proj_w[i]); }
    if (i < 65536) { wfc1[i] = f2bs(fc1_w[i]); wfc2[i] = f2bs(fc2_w[i]); }
}

// ---------- kernel 1: LN1 + QV GEMM + K proj, 32 px/block, 512 thr ----------
// XCD swizzle: block b -> pixels (b&7)*2048 + (b>>3)*32 (band of 16 image rows
// per XCD under round-robin blockIdx->XCD dispatch).
__global__ __launch_bounds__(512, 6) void k_qkv(
    const float* __restrict__ x, const float* __restrict__ y,
    const short* __restrict__ wqv, const float* __restrict__ qv_b,
    const short* __restrict__ wk, const float* __restrict__ k_b,
    const float* __restrict__ n1_w, const float* __restrict__ n1_b,
    bf16* __restrict__ qb, bf16* __restrict__ vb, bf16* __restrict__ kb) {
    __shared__ float xr[32][132];
    __shared__ short xn[32][136];
    __shared__ short yb[32][136];
    __shared__ float muA[32], riA[32];
    const int t = threadIdx.x;
    const int pix0 = (blockIdx.x & 7) * 2048 + (blockIdx.x >> 3) * 32;
    for (int e = t; e < 32 * 128; e += 512) {
        const int r = e >> 7, c = e & 127;
        xr[r][c] = x[(pix0 + r) * C + c];
        yb[r][c] = f2bs(y[(pix0 + r) * C + c]);
    }
    __syncthreads();
    if (t < 256) {
        const int r = t >> 3, s = t & 7;
        float sm = 0.f, sq = 0.f;
        for (int i = 0; i < 16; i++) { float v = xr[r][s * 16 + i]; sm += v; sq += v * v; }
        for (int m = 1; m < 8; m <<= 1) { sm += __shfl_xor(sm, m, 64); sq += __shfl_xor(sq, m, 64); }
        if (s == 0) {
            const float mu = sm * (1.f / 128.f);
            const float var = sq * (1.f / 128.f) - mu * mu;
            muA[r] = mu; riA[r] = rsqrtf(var + 1e-5f);
        }
    }
    __syncthreads();
    for (int e = t; e < 32 * 128; e += 512) {
        const int r = e >> 7, c = e & 127;
        xn[r][c] = f2bs((xr[r][c] - muA[r]) * riA[r] * n1_w[c] + n1_b[c]);
    }
    __syncthreads();
    const int wave = t >> 6, lane = t & 63, quad = lane >> 4, l15 = lane & 15;
    const int mt = wave & 1, wv = wave >> 1;
    const float scale = 0.1767766952966369f;   // 1/sqrt(32)
    // ---- qv GEMM: A preloaded once, 4 unrolled n-tiles ----
    {
        bf16x8 aA[4];
#pragma unroll
        for (int kt = 0; kt < 4; kt++)
            aA[kt] = *(const bf16x8*)&xn[mt * 16 + l15][kt * 32 + quad * 8];
#pragma unroll
        for (int s = 0; s < 4; s++) {
            const int n = (wv * 4 + s) * 16 + l15;
            f32x4 acc = {0.f, 0.f, 0.f, 0.f};
#pragma unroll
            for (int kt = 0; kt < 4; kt++) {
                bf16x8 b = *(const bf16x8*)&wqv[n * C + kt * 32 + quad * 8];
                acc = __builtin_amdgcn_mfma_f32_16x16x32_bf16(aA[kt], b, acc, 0, 0, 0);
            }
            const float bias = qv_b[n];
#pragma unroll
            for (int r = 0; r < 4; r++) {
                const int m = mt * 16 + quad * 4 + r;
                const float v = acc[r] + bias;
                if (n < C) qb[(pix0 + m) * C + n] = __float2bfloat16(v * scale);
                else       vb[(pix0 + m) * C + (n - C)] = __float2bfloat16(v);
            }
        }
    }
    // ---- k GEMM: A preloaded, 2 n-tiles, interleaved accumulators ----
    {
        bf16x8 aY[4];
#pragma unroll
        for (int kt = 0; kt < 4; kt++)
            aY[kt] = *(const bf16x8*)&yb[mt * 16 + l15][kt * 32 + quad * 8];
        const int n0 = (wv * 2) * 16 + l15, n1 = (wv * 2 + 1) * 16 + l15;
        f32x4 a0 = {0.f, 0.f, 0.f, 0.f}, a1 = {0.f, 0.f, 0.f, 0.f};
#pragma unroll
        for (int kt = 0; kt < 4; kt++) {
            bf16x8 b0 = *(const bf16x8*)&wk[n0 * C + kt * 32 + quad * 8];
            bf16x8 b1 = *(const bf16x8*)&wk[n1 * C + kt * 32 + quad * 8];
            a0 = __builtin_amdgcn_mfma_f32_16x16x32_bf16(aY[kt], b0, a0, 0, 0, 0);
            a1 = __builtin_amdgcn_mfma_f32_16x16x32_bf16(aY[kt], b1, a1, 0, 0, 0);
        }
        const float b0s = k_b[n0], b1s = k_b[n1];
#pragma unroll
        for (int r = 0; r < 4; r++) {
            const int m = mt * 16 + quad * 4 + r;
            kb[(pix0 + m) * C + n0] = __float2bfloat16(a0[r] + b0s);
            kb[(pix0 + m) * C + n1] = __float2bfloat16(a1[r] + b1s);
        }
    }
}

// ---------- kernel 2: fused attention + proj + residual + LN2 + MLP ----------
// XCD swizzle: block b -> tile-row (b&7)*4 + ((b>>3)>>5), tile-col (b>>3)&31.
// Same 16-image-row band as k_qkv's (b&7) producer blocks.
__global__ __launch_bounds__(256) void k_fam(
    const bf16* __restrict__ qb, const bf16* __restrict__ kb,
    const bf16* __restrict__ vb, const float* __restrict__ rpb,
    const float* __restrict__ x,
    const short* __restrict__ wproj, const float* __restrict__ proj_b,
    const float* __restrict__ n2_w, const float* __restrict__ n2_b,
    const short* __restrict__ wfc1, const float* __restrict__ fc1_b,
    const short* __restrict__ wfc2, const float* __restrict__ fc2_b,
    float* __restrict__ out) {
    __shared__ short KP[13200];
    __shared__ short Vl[13200];
    __shared__ float muA[16], riA[16];
    short* const Pm  = KP;            // 64 x 136
    short* const aoL = KP + 8704;     // 16 x 136
    short* const x1b = KP + 10880;    // 16 x 136
    short* const hb  = Vl;            // 16 x 520
    short* const xnb = Vl + 8320;     // 16 x 136
    const int t = threadIdx.x;
    const int h = t >> 6, lane = t & 63, quad = lane >> 4, l15 = lane & 15;
    const int s_ = blockIdx.x >> 3;
    const int i0 = ((blockIdx.x & 7) * 4 + (s_ >> 5)) * 4;
    const int j0 = (s_ & 31) * 4;
    const int rs = min(max(i0 - 3, 0), 118);
    const int cs = min(max(j0 - 3, 0), 118);
    // ---- phase 1: stage K,V unions ----
    for (int u = t; u < 100 * 16 * 2; u += 256) {
        const int tv = (u >= 1600) ? 1 : 0;
        const int uu = tv ? u - 1600 : u;
        const int r = uu >> 4, seg = uu & 15;
        const size_t g = (size_t)((rs + r / 10) * HW + cs + r % 10) * C + seg * 8;
        const uint4 d = *(const uint4*)((tv ? vb : kb) + g);
        *(uint4*)&(tv ? Vl : KP)[r * 132 + seg * 8] = d;
    }
    __syncthreads();
    // ---- phase 2: QK^T + bias/mask + softmax (wave = head) ----
    const int pA = (i0 + (l15 >> 2)) * HW + j0 + (l15 & 3);
    const bf16x8 aQ = *(const bf16x8*)(qb + (size_t)pA * C + h * HD + quad * 8);
    f32x4 S[7];
    int aiL[7], ajL[7]; bool inb[7];
#pragma unroll
    for (int nt = 0; nt < 7; nt++) {
        const int nb = nt * 16 + l15;
        aiL[nt] = rs + nb / 10;
        ajL[nt] = cs + nb % 10;
        inb[nt] = nb < 100;
        const bf16x8 bK = *(const bf16x8*)&KP[(nt * 16 + l15) * 132 + h * HD + quad * 8];
        f32x4 z = {0.f, 0.f, 0.f, 0.f};
        S[nt] = __builtin_amdgcn_mfma_f32_16x16x32_bf16(aQ, bK, z, 0, 0, 0);
    }
    const float* rpbh = rpb + h * 169;
    float smx[4];
#pragma unroll
    for (int r = 0; r < 4; r++) {
        const int m = quad * 4 + r;
        const int i = i0 + (m >> 2), j = j0 + (m & 3);
        const int shi = min(max(i - 3, 0), 121);
        const int swj = min(max(j - 3, 0), 121);
        float best = -1e30f;
#pragma unroll
        for (int nt = 0; nt < 7; nt++) {
            const int ai = aiL[nt], aj = ajL[nt];
            const bool valid = inb[nt] & (ai >= shi) & (ai <= shi + 6) & (aj >= swj) & (aj <= swj + 6);
            const int ri = min(max(ai - i + 6, 0), 12);
            const int rj = min(max(aj - j + 6, 0), 12);
            const float v = valid ? (S[nt][r] + rpbh[ri * 13 + rj]) : -1e30f;
            S[nt][r] = v;
            best = fmaxf(best, v);
        }
        for (int msk = 1; msk < 16; msk <<= 1) best = fmaxf(best, __shfl_xor(best, msk, 64));
        float s = 0.f;
#pragma unroll
        for (int nt = 0; nt < 7; nt++) {
            const float e = __expf(S[nt][r] - best);
            S[nt][r] = e;
            s += e;
        }
        for (int msk = 1; msk < 16; msk <<= 1) s += __shfl_xor(s, msk, 64);
        smx[r] = 1.f / s;
    }
    __syncthreads();
    // ---- phase 3: P -> Pm ----
#pragma unroll
    for (int r = 0; r < 4; r++) {
        short* prow = &Pm[(h * 16 + quad * 4 + r) * 136];
#pragma unroll
        for (int nt = 0; nt < 7; nt++)
            prow[nt * 16 + l15] = f2bs(S[nt][r] * smx[r]);
        prow[112 + l15] = 0;
    }
    __syncthreads();
    // ---- phase 4: PV -> aoL ----
    f32x4 O0 = {0.f, 0.f, 0.f, 0.f}, O1 = {0.f, 0.f, 0.f, 0.f};
#pragma unroll
    for (int kt = 0; kt < 4; kt++) {
        const bf16x8 aP = *(const bf16x8*)&Pm[(h * 16 + l15) * 136 + kt * 32 + quad * 8];
#pragma unroll
        for (int nt2 = 0; nt2 < 2; nt2++) {
            bf16x8 bV;
            const int ch = h * HD + nt2 * 16 + l15;
#pragma unroll
            for (int jj = 0; jj < 8; jj++) {
                const int nbr = kt * 32 + quad * 8 + jj;
                bV[jj] = (nbr < 100) ? Vl[nbr * 132 + ch] : (short)0;
            }
            if (nt2 == 0) O0 = __builtin_amdgcn_mfma_f32_16x16x32_bf16(aP, bV, O0, 0, 0, 0);
            else          O1 = __builtin_amdgcn_mfma_f32_16x16x32_bf16(aP, bV, O1, 0, 0, 0);
        }
    }
#pragma unroll
    for (int r = 0; r < 4; r++) {
        const int m = quad * 4 + r;
        aoL[m * 136 + h * HD + l15] = f2bs(O0[r]);
        aoL[m * 136 + h * HD + 16 + l15] = f2bs(O1[r]);
    }
    __syncthreads();
    // ---- phase 5: proj + residual -> x1b ----
    {
        bf16x8 aO[4];
#pragma unroll
        for (int kt = 0; kt < 4; kt++)
            aO[kt] = *(const bf16x8*)&aoL[l15 * 136 + kt * 32 + quad * 8];
        const int n0 = h * 16 + l15, n1 = (h + 4) * 16 + l15;
        f32x4 a0 = {0.f, 0.f, 0.f, 0.f}, a1 = {0.f, 0.f, 0.f, 0.f};
#pragma unroll
        for (int kt = 0; kt < 4; kt++) {
            bf16x8 b0 = *(const bf16x8*)&wproj[n0 * C + kt * 32 + quad * 8];
            bf16x8 b1 = *(const bf16x8*)&wproj[n1 * C + kt * 32 + quad * 8];
            a0 = __builtin_amdgcn_mfma_f32_16x16x32_bf16(aO[kt], b0, a0, 0, 0, 0);
            a1 = __builtin_amdgcn_mfma_f32_16x16x32_bf16(aO[kt], b1, a1, 0, 0, 0);
        }
        const float b0s = proj_b[n0], b1s = proj_b[n1];
#pragma unroll
        for (int r = 0; r < 4; r++) {
            const int m = quad * 4 + r;
            const int p = (i0 + (m >> 2)) * HW + j0 + (m & 3);
            x1b[m * 136 + n0] = f2bs(x[(size_t)p * C + n0] + a0[r] + b0s);
            x1b[m * 136 + n1] = f2bs(x[(size_t)p * C + n1] + a1[r] + b1s);
        }
    }
    __syncthreads();
    // ---- phase 6: LN2 stats ----
    if (t < 128) {
        const int r = t >> 3, s = t & 7;
        float sm = 0.f, sq = 0.f;
        for (int i = 0; i < 16; i++) { float v = bs2f(x1b[r * 136 + s * 16 + i]); sm += v; sq += v * v; }
        for (int m = 1; m < 8; m <<= 1) { sm += __shfl_xor(sm, m, 64); sq += __shfl_xor(sq, m, 64); }
        if (s == 0) {
            const float mu = sm * (1.f / 128.f);
            const float var = sq * (1.f / 128.f) - mu * mu;
            muA[r] = mu; riA[r] = rsqrtf(var + 1e-5f);
        }
    }
    __syncthreads();
    // ---- phase 7: xn = LN(x1) -> xnb ----
    for (int e = t; e < 16 * 128; e += 256) {
        const int r = e >> 7, c = e & 127;
        xnb[r * 136 + c] = f2bs((bs2f(x1b[r * 136 + c]) - muA[r]) * riA[r] * n2_w[c] + n2_b[c]);
    }
    __syncthreads();
    // ---- phase 8: fc1 + gelu -> hb ----
    {
        bf16x8 aX[4];
#pragma unroll
        for (int kt = 0; kt < 4; kt++)
            aX[kt] = *(const bf16x8*)&xnb[l15 * 136 + kt * 32 + quad * 8];
#pragma unroll
        for (int a = 0; a < 4; a++) {
            const int n0 = (h + 8 * a) * 16 + l15, n1 = (h + 8 * a + 4) * 16 + l15;
            f32x4 a0 = {0.f, 0.f, 0.f, 0.f}, a1 = {0.f, 0.f, 0.f, 0.f};
#pragma unroll
            for (int kt = 0; kt < 4; kt++) {
                bf16x8 b0 = *(const bf16x8*)&wfc1[n0 * C + kt * 32 + quad * 8];
                bf16x8 b1 = *(const bf16x8*)&wfc1[n1 * C + kt * 32 + quad * 8];
                a0 = __builtin_amdgcn_mfma_f32_16x16x32_bf16(aX[kt], b0, a0, 0, 0, 0);
                a1 = __builtin_amdgcn_mfma_f32_16x16x32_bf16(aX[kt], b1, a1, 0, 0, 0);
            }
            const float b0s = fc1_b[n0], b1s = fc1_b[n1];
#pragma unroll
            for (int r = 0; r < 4; r++) {
                hb[(quad * 4 + r) * 520 + n0] = f2bs(gelu_f(a0[r] + b0s));
                hb[(quad * 4 + r) * 520 + n1] = f2bs(gelu_f(a1[r] + b1s));
            }
        }
    }
    __syncthreads();
    // ---- phase 9: fc2 + residual -> out ----
    {
        const int n0 = h * 16 + l15, n1 = (h + 4) * 16 + l15;
        f32x4 a0 = {0.f, 0.f, 0.f, 0.f}, a1 = {0.f, 0.f, 0.f, 0.f};
#pragma unroll
        for (int kt = 0; kt < 16; kt++) {
            const bf16x8 aP = *(const bf16x8*)&hb[l15 * 520 + kt * 32 + quad * 8];
            bf16x8 b0 = *(const bf16x8*)&wfc2[n0 * 512 + kt * 32 + quad * 8];
            bf16x8 b1 = *(const bf16x8*)&wfc2[n1 * 512 + kt * 32 + quad * 8];
            a0 = __builtin_amdgcn_mfma_f32_16x16x32_bf16(aP, b0, a0, 0, 0, 0);
            a1 = __builtin_amdgcn_mfma_f32_16x16x32_bf16(aP, b1, a1, 0, 0, 0);
        }
        const float b0s = fc2_b[n0], b1s = fc2_b[n1];
#pragma unroll
        for (int r = 0; r < 4; r++) {
            const int m = quad * 4 + r;
            const int p = (i0 + (m >> 2)) * HW + j0 + (m & 3);
            out[(size_t)p * C + n0] = a0[r] + b0s + bs2f(x1b[m * 136 + n0]);
            out[(size_t)p * C + n1] = a1[r] + b1s + bs2f(x1b[m * 136 + n1]);
        }
    }
}

extern "C" void kernel_launch(void* const* d_in, const int* in_sizes, int n_in,
                              void* d_out, int out_size, void* d_ws, size_t ws_size,
                              hipStream_t stream) {
    const float* x      = (const float*)d_in[0];
    const float* y      = (const float*)d_in[1];
    const float* qv_w   = (const float*)d_in[2];
    const float* qv_b   = (const float*)d_in[3];
    const float* k_w    = (const float*)d_in[4];
    const float* k_b    = (const float*)d_in[5];
    const float* rpb    = (const float*)d_in[6];
    const float* proj_w = (const float*)d_in[7];
    const float* proj_b = (const float*)d_in[8];
    const float* n1_w   = (const float*)d_in[9];
    const float* n1_b   = (const float*)d_in[10];
    const float* n2_w   = (const float*)d_in[11];
    const float* n2_b   = (const float*)d_in[12];
    const float* fc1_w  = (const float*)d_in[13];
    const float* fc1_b  = (const float*)d_in[14];
    const float* fc2_w  = (const float*)d_in[15];
    const float* fc2_b  = (const float*)d_in[16];
    float* out = (float*)d_out;

    bf16* qb  = (bf16*)d_ws;
    bf16* vb  = qb + (size_t)N_PIX * C;
    bf16* kb  = vb + (size_t)N_PIX * C;
    short* wqv  = (short*)(kb + (size_t)N_PIX * C); // 32768
    short* wk   = wqv + 32768;                      // 16384
    short* wproj= wk + 16384;                       // 16384
    short* wfc1 = wproj + 16384;                    // 65536
    short* wfc2 = wfc1 + 65536;                     // 65536  (total ~12.4 MB)

    k_wconv<<<256, 256, 0, stream>>>(qv_w, k_w, proj_w, fc1_w, fc2_w,
                                     wqv, wk, wproj, wfc1, wfc2);
    k_qkv<<<N_PIX / 32, 512, 0, stream>>>(x, y, wqv, qv_b, wk, k_b, n1_w, n1_b, qb, vb, kb);
    k_fam<<<1024, 256, 0, stream>>>(qb, kb, vb, rpb, x, wproj, proj_b, n2_w, n2_b,
                                    wfc1, fc1_b, wfc2, fc2_b, out);
}

// Round 14
// 165.858 us; speedup vs baseline: 1.0603x; 1.0581x over previous
//
#include <hip/hip_runtime.h>
#include <hip/hip_bf16.h>

// CrossNATBlock2D: B=1, H=W=128, C=128, HEADS=4, HD=32, K=7  (fp32 I/O)
// R14: one-dispatch-round kernels. k_qkv: 64 px/block (256 blocks, 512 thr).
// k_fam: 8x4 tile = 32 px/block (512 blocks, 512 thr, union 14x10=140 rows,
// LDS 74.5 KB -> 2 blocks/CU -> single round). XCD band swizzle kept.

#define N_PIX 16384
#define C 128
#define HEADS 4
#define HD 32
#define HW 128

typedef __hip_bfloat16 bf16;
typedef __attribute__((ext_vector_type(8))) short bf16x8;
typedef __attribute__((ext_vector_type(4))) float f32x4;

__device__ __forceinline__ short f2bs(float f) {
    bf16 h = __float2bfloat16(f);
    return (short)__bfloat16_as_ushort(h);
}
__device__ __forceinline__ float bs2f(short s) {
    __hip_bfloat16_raw r; r.x = (unsigned short)s;
    return __bfloat162float(__hip_bfloat16(r));
}
__device__ __forceinline__ float gelu_f(float v) {
    const float z = 1.5957691216f * (v + 0.044715f * v * v * v);
    return v / (1.f + __expf(-z));
}

// ---------- kernel 0: convert weights fp32 -> bf16 into ws ----------
__global__ __launch_bounds__(256) void k_wconv(
    const float* __restrict__ qv_w, const float* __restrict__ k_w,
    const float* __restrict__ proj_w, const float* __restrict__ fc1_w,
    const float* __restrict__ fc2_w,
    short* __restrict__ wqv, short* __restrict__ wk, short* __restrict__ wproj,
    short* __restrict__ wfc1, short* __restrict__ wfc2) {
    const int i = blockIdx.x * 256 + threadIdx.x;
    if (i < 32768) wqv[i] = f2bs(qv_w[i]);
    if (i < 16384) { wk[i] = f2bs(k_w[i]); wproj[i] = f2bs(proj_w[i]); }
    if (i < 65536) { wfc1[i] = f2bs(fc1_w[i]); wfc2[i] = f2bs(fc2_w[i]); }
}

// ---------- kernel 1: LN1 + QV GEMM + K proj, 64 px/block, 512 thr ----------
// swizzle: block b -> pixels (b&7)*2048 + (b>>3)*64
__global__ __launch_bounds__(512, 2) void k_qkv(
    const float* __restrict__ x, const float* __restrict__ y,
    const short* __restrict__ wqv, const float* __restrict__ qv_b,
    const short* __restrict__ wk, const float* __restrict__ k_b,
    const float* __restrict__ n1_w, const float* __restrict__ n1_b,
    bf16* __restrict__ qb, bf16* __restrict__ vb, bf16* __restrict__ kb) {
    __shared__ float xr[64][132];
    __shared__ short xn[64][136];
    __shared__ short yb[64][136];
    __shared__ float muA[64], riA[64];
    const int t = threadIdx.x;
    const int pix0 = (blockIdx.x & 7) * 2048 + (blockIdx.x >> 3) * 64;
    for (int e = t; e < 64 * 128; e += 512) {
        const int r = e >> 7, c = e & 127;
        xr[r][c] = x[(pix0 + r) * C + c];
        yb[r][c] = f2bs(y[(pix0 + r) * C + c]);
    }
    __syncthreads();
    {
        const int r = t >> 3, s = t & 7;   // 8 lanes (same wave) per row
        float sm = 0.f, sq = 0.f;
        for (int i = 0; i < 16; i++) { float v = xr[r][s * 16 + i]; sm += v; sq += v * v; }
        for (int m = 1; m < 8; m <<= 1) { sm += __shfl_xor(sm, m, 64); sq += __shfl_xor(sq, m, 64); }
        if (s == 0) {
            const float mu = sm * (1.f / 128.f);
            const float var = sq * (1.f / 128.f) - mu * mu;
            muA[r] = mu; riA[r] = rsqrtf(var + 1e-5f);
        }
    }
    __syncthreads();
    for (int e = t; e < 64 * 128; e += 512) {
        const int r = e >> 7, c = e & 127;
        xn[r][c] = f2bs((xr[r][c] - muA[r]) * riA[r] * n1_w[c] + n1_b[c]);
    }
    __syncthreads();
    const int wave = t >> 6, lane = t & 63, quad = lane >> 4, l15 = lane & 15;
    const int mt = wave >> 1, half = wave & 1;   // mt in [0,4): 4 m-tiles of 16
    const float scale = 0.1767766952966369f;     // 1/sqrt(32)
    // ---- qv GEMM: 16 n-tiles split 2 ways -> 8 per wave ----
    {
        bf16x8 aA[4];
#pragma unroll
        for (int kt = 0; kt < 4; kt++)
            aA[kt] = *(const bf16x8*)&xn[mt * 16 + l15][kt * 32 + quad * 8];
#pragma unroll
        for (int s = 0; s < 8; s++) {
            const int n = (half + 2 * s) * 16 + l15;
            f32x4 acc = {0.f, 0.f, 0.f, 0.f};
#pragma unroll
            for (int kt = 0; kt < 4; kt++) {
                bf16x8 b = *(const bf16x8*)&wqv[n * C + kt * 32 + quad * 8];
                acc = __builtin_amdgcn_mfma_f32_16x16x32_bf16(aA[kt], b, acc, 0, 0, 0);
            }
            const float bias = qv_b[n];
#pragma unroll
            for (int r = 0; r < 4; r++) {
                const int m = mt * 16 + quad * 4 + r;
                const float v = acc[r] + bias;
                if (n < C) qb[(pix0 + m) * C + n] = __float2bfloat16(v * scale);
                else       vb[(pix0 + m) * C + (n - C)] = __float2bfloat16(v);
            }
        }
    }
    // ---- k GEMM: 8 n-tiles split 2 ways -> 4 per wave, 2-way interleave ----
    {
        bf16x8 aY[4];
#pragma unroll
        for (int kt = 0; kt < 4; kt++)
            aY[kt] = *(const bf16x8*)&yb[mt * 16 + l15][kt * 32 + quad * 8];
#pragma unroll
        for (int s = 0; s < 2; s++) {
            const int n0 = (half + 2 * (2 * s)) * 16 + l15;
            const int n1 = (half + 2 * (2 * s + 1)) * 16 + l15;
            f32x4 a0 = {0.f, 0.f, 0.f, 0.f}, a1 = {0.f, 0.f, 0.f, 0.f};
#pragma unroll
            for (int kt = 0; kt < 4; kt++) {
                bf16x8 b0 = *(const bf16x8*)&wk[n0 * C + kt * 32 + quad * 8];
                bf16x8 b1 = *(const bf16x8*)&wk[n1 * C + kt * 32 + quad * 8];
                a0 = __builtin_amdgcn_mfma_f32_16x16x32_bf16(aY[kt], b0, a0, 0, 0, 0);
                a1 = __builtin_amdgcn_mfma_f32_16x16x32_bf16(aY[kt], b1, a1, 0, 0, 0);
            }
            const float b0s = k_b[n0], b1s = k_b[n1];
#pragma unroll
            for (int r = 0; r < 4; r++) {
                const int m = mt * 16 + quad * 4 + r;
                kb[(pix0 + m) * C + n0] = __float2bfloat16(a0[r] + b0s);
                kb[(pix0 + m) * C + n1] = __float2bfloat16(a1[r] + b1s);
            }
        }
    }
}

// ---------- kernel 2: fused attention + proj + residual + LN2 + MLP ----------
// 8x4 tile (32 px), 512 thr: wave = (mt<<2)|head. Union 14x10 = 140 rows.
// swizzle: b&7 = XCD band; tile_i = (b&7)*2 + ((b>>3)>>5), tile_j = (b>>3)&31.
__global__ __launch_bounds__(512, 2) void k_fam(
    const bf16* __restrict__ qb, const bf16* __restrict__ kb,
    const bf16* __restrict__ vb, const float* __restrict__ rpb,
    const float* __restrict__ x,
    const short* __restrict__ wproj, const float* __restrict__ proj_b,
    const float* __restrict__ n2_w, const float* __restrict__ n2_b,
    const short* __restrict__ wfc1, const float* __restrict__ fc1_b,
    const short* __restrict__ wfc2, const float* __restrict__ fc2_b,
    float* __restrict__ out) {
    __shared__ short KP[19008];   // K 140x132 -> P 128x144
    __shared__ short Vl[19008];   // V 140x132 -> aoL/x1b/xn/hb region partner
    __shared__ float muA[32], riA[32];
    short* const Pm  = KP;            // 128 x 144 (18432)
    short* const aoL = KP;            // 32 x 136 (after PV)
    short* const x1b = KP + 4352;     // 32 x 136
    short* const xnb = KP + 8704;     // 32 x 136
    short* const hb  = Vl;            // 32 x 520 (16640)
    const int t = threadIdx.x;
    const int wave = t >> 6, lane = t & 63, quad = lane >> 4, l15 = lane & 15;
    const int h = wave & 3, mt = wave >> 2;
    const int s_ = blockIdx.x >> 3;
    const int i0 = ((blockIdx.x & 7) * 2 + (s_ >> 5)) * 8;
    const int j0 = (s_ & 31) * 4;
    const int rs = min(max(i0 - 3, 0), 114);   // union rows [rs, rs+13]
    const int cs = min(max(j0 - 3, 0), 118);   // union cols [cs, cs+9]
    // ---- phase 1: stage K,V unions (140 rows x 128 ch) ----
    for (int u = t; u < 140 * 16 * 2; u += 512) {
        const int tv = (u >= 2240) ? 1 : 0;
        const int uu = tv ? u - 2240 : u;
        const int r = uu >> 4, seg = uu & 15;
        const size_t g = (size_t)((rs + r / 10) * HW + cs + r % 10) * C + seg * 8;
        const uint4 d = *(const uint4*)((tv ? vb : kb) + g);
        *(uint4*)&(tv ? Vl : KP)[r * 132 + seg * 8] = d;
    }
    __syncthreads();
    // ---- phase 2: QK^T + bias/mask + softmax; wave = (mt, head) ----
    const int mA = mt * 16 + l15;
    const int pA = (i0 + (mA >> 2)) * HW + j0 + (mA & 3);
    const bf16x8 aQ = *(const bf16x8*)(qb + (size_t)pA * C + h * HD + quad * 8);
    f32x4 S[9];
#pragma unroll
    for (int nt = 0; nt < 9; nt++) {
        const bf16x8 bK = *(const bf16x8*)&KP[(nt * 16 + l15) * 132 + h * HD + quad * 8];
        f32x4 z = {0.f, 0.f, 0.f, 0.f};
        S[nt] = __builtin_amdgcn_mfma_f32_16x16x32_bf16(aQ, bK, z, 0, 0, 0);
    }
    const int nbL = l15;  // per-lane geometry base
    const float* rpbh = rpb + h * 169;
    float smx[4];
#pragma unroll
    for (int r = 0; r < 4; r++) {
        const int m = mt * 16 + quad * 4 + r;
        const int i = i0 + (m >> 2), j = j0 + (m & 3);
        const int shi = min(max(i - 3, 0), 121);
        const int swj = min(max(j - 3, 0), 121);
        float best = -1e30f;
#pragma unroll
        for (int nt = 0; nt < 9; nt++) {
            const int nb = nt * 16 + nbL;
            const int ai = rs + nb / 10, aj = cs + nb % 10;
            const bool valid = (nb < 140) & (ai >= shi) & (ai <= shi + 6) & (aj >= swj) & (aj <= swj + 6);
            const int ri = min(max(ai - i + 6, 0), 12);
            const int rj = min(max(aj - j + 6, 0), 12);
            const float v = valid ? (S[nt][r] + rpbh[ri * 13 + rj]) : -1e30f;
            S[nt][r] = v;
            best = fmaxf(best, v);
        }
        for (int msk = 1; msk < 16; msk <<= 1) best = fmaxf(best, __shfl_xor(best, msk, 64));
        float s = 0.f;
#pragma unroll
        for (int nt = 0; nt < 9; nt++) {
            const float e = __expf(S[nt][r] - best);
            S[nt][r] = e;
            s += e;
        }
        for (int msk = 1; msk < 16; msk <<= 1) s += __shfl_xor(s, msk, 64);
        smx[r] = 1.f / s;
    }
    __syncthreads();   // all K reads done
    // ---- phase 3: P -> Pm (rows wave*16.., stride 144; invalid cols = 0) ----
#pragma unroll
    for (int r = 0; r < 4; r++) {
        short* prow = &Pm[(wave * 16 + quad * 4 + r) * 144];
#pragma unroll
        for (int nt = 0; nt < 9; nt++)
            prow[nt * 16 + l15] = f2bs(S[nt][r] * smx[r]);
    }
    __syncthreads();
    // ---- phase 4: PV (kt tail gated by nbr<140; aP tail cols x 0) ----
    f32x4 O0 = {0.f, 0.f, 0.f, 0.f}, O1 = {0.f, 0.f, 0.f, 0.f};
#pragma unroll
    for (int kt = 0; kt < 5; kt++) {
        const bf16x8 aP = *(const bf16x8*)&Pm[(wave * 16 + l15) * 144 + kt * 32 + quad * 8];
#pragma unroll
        for (int nt2 = 0; nt2 < 2; nt2++) {
            bf16x8 bV;
            const int ch = h * HD + nt2 * 16 + l15;
#pragma unroll
            for (int jj = 0; jj < 8; jj++) {
                const int nbr = kt * 32 + quad * 8 + jj;
                bV[jj] = (nbr < 140) ? Vl[nbr * 132 + ch] : (short)0;
            }
            if (nt2 == 0) O0 = __builtin_amdgcn_mfma_f32_16x16x32_bf16(aP, bV, O0, 0, 0, 0);
            else          O1 = __builtin_amdgcn_mfma_f32_16x16x32_bf16(aP, bV, O1, 0, 0, 0);
        }
    }
    __syncthreads();   // all P/V reads done; K/V regions now dead
    // ---- phase 5: ao -> aoL ----
#pragma unroll
    for (int r = 0; r < 4; r++) {
        const int m = mt * 16 + quad * 4 + r;
        aoL[m * 136 + h * HD + l15] = f2bs(O0[r]);
        aoL[m * 136 + h * HD + 16 + l15] = f2bs(O1[r]);
    }
    __syncthreads();
    // ---- phase 6: proj + residual -> x1b (2 n-tiles per wave, interleaved) ----
    {
        bf16x8 aO[4];
#pragma unroll
        for (int kt = 0; kt < 4; kt++)
            aO[kt] = *(const bf16x8*)&aoL[(mt * 16 + l15) * 136 + kt * 32 + quad * 8];
        const int n0 = h * 16 + l15, n1 = (h + 4) * 16 + l15;
        f32x4 a0 = {0.f, 0.f, 0.f, 0.f}, a1 = {0.f, 0.f, 0.f, 0.f};
#pragma unroll
        for (int kt = 0; kt < 4; kt++) {
            bf16x8 b0 = *(const bf16x8*)&wproj[n0 * C + kt * 32 + quad * 8];
            bf16x8 b1 = *(const bf16x8*)&wproj[n1 * C + kt * 32 + quad * 8];
            a0 = __builtin_amdgcn_mfma_f32_16x16x32_bf16(aO[kt], b0, a0, 0, 0, 0);
            a1 = __builtin_amdgcn_mfma_f32_16x16x32_bf16(aO[kt], b1, a1, 0, 0, 0);
        }
        const float b0s = proj_b[n0], b1s = proj_b[n1];
#pragma unroll
        for (int r = 0; r < 4; r++) {
            const int m = mt * 16 + quad * 4 + r;
            const int p = (i0 + (m >> 2)) * HW + j0 + (m & 3);
            x1b[m * 136 + n0] = f2bs(x[(size_t)p * C + n0] + a0[r] + b0s);
            x1b[m * 136 + n1] = f2bs(x[(size_t)p * C + n1] + a1[r] + b1s);
        }
    }
    __syncthreads();
    // ---- phase 7: LN2 stats (32 rows x 8 lanes, waves 0-3) ----
    if (t < 256) {
        const int r = t >> 3, s = t & 7;
        float sm = 0.f, sq = 0.f;
        for (int i = 0; i < 16; i++) { float v = bs2f(x1b[r * 136 + s * 16 + i]); sm += v; sq += v * v; }
        for (int m = 1; m < 8; m <<= 1) { sm += __shfl_xor(sm, m, 64); sq += __shfl_xor(sq, m, 64); }
        if (s == 0) {
            const float mu = sm * (1.f / 128.f);
            const float var = sq * (1.f / 128.f) - mu * mu;
            muA[r] = mu; riA[r] = rsqrtf(var + 1e-5f);
        }
    }
    __syncthreads();
    // ---- phase 8: xn = LN(x1) -> xnb ----
    for (int e = t; e < 32 * 128; e += 512) {
        const int r = e >> 7, c = e & 127;
        xnb[r * 136 + c] = f2bs((bs2f(x1b[r * 136 + c]) - muA[r]) * riA[r] * n2_w[c] + n2_b[c]);
    }
    __syncthreads();
    // ---- phase 9: fc1 + gelu -> hb (8 n-tiles/wave, 2-way interleave) ----
    {
        bf16x8 aX[4];
#pragma unroll
        for (int kt = 0; kt < 4; kt++)
            aX[kt] = *(const bf16x8*)&xnb[(mt * 16 + l15) * 136 + kt * 32 + quad * 8];
#pragma unroll
        for (int a = 0; a < 4; a++) {
            const int n0 = (h + 8 * a) * 16 + l15, n1 = (h + 8 * a + 4) * 16 + l15;
            f32x4 a0 = {0.f, 0.f, 0.f, 0.f}, a1 = {0.f, 0.f, 0.f, 0.f};
#pragma unroll
            for (int kt = 0; kt < 4; kt++) {
                bf16x8 b0 = *(const bf16x8*)&wfc1[n0 * C + kt * 32 + quad * 8];
                bf16x8 b1 = *(const bf16x8*)&wfc1[n1 * C + kt * 32 + quad * 8];
                a0 = __builtin_amdgcn_mfma_f32_16x16x32_bf16(aX[kt], b0, a0, 0, 0, 0);
                a1 = __builtin_amdgcn_mfma_f32_16x16x32_bf16(aX[kt], b1, a1, 0, 0, 0);
            }
            const float b0s = fc1_b[n0], b1s = fc1_b[n1];
#pragma unroll
            for (int r = 0; r < 4; r++) {
                const int m = mt * 16 + quad * 4 + r;
                hb[m * 520 + n0] = f2bs(gelu_f(a0[r] + b0s));
                hb[m * 520 + n1] = f2bs(gelu_f(a1[r] + b1s));
            }
        }
    }
    __syncthreads();
    // ---- phase 10: fc2 + residual -> out ----
    {
        const int n0 = h * 16 + l15, n1 = (h + 4) * 16 + l15;
        f32x4 a0 = {0.f, 0.f, 0.f, 0.f}, a1 = {0.f, 0.f, 0.f, 0.f};
#pragma unroll
        for (int kt = 0; kt < 16; kt++) {
            const bf16x8 aP = *(const bf16x8*)&hb[(mt * 16 + l15) * 520 + kt * 32 + quad * 8];
            bf16x8 b0 = *(const bf16x8*)&wfc2[n0 * 512 + kt * 32 + quad * 8];
            bf16x8 b1 = *(const bf16x8*)&wfc2[n1 * 512 + kt * 32 + quad * 8];
            a0 = __builtin_amdgcn_mfma_f32_16x16x32_bf16(aP, b0, a0, 0, 0, 0);
            a1 = __builtin_amdgcn_mfma_f32_16x16x32_bf16(aP, b1, a1, 0, 0, 0);
        }
        const float b0s = fc2_b[n0], b1s = fc2_b[n1];
#pragma unroll
        for (int r = 0; r < 4; r++) {
            const int m = mt * 16 + quad * 4 + r;
            const int p = (i0 + (m >> 2)) * HW + j0 + (m & 3);
            out[(size_t)p * C + n0] = a0[r] + b0s + bs2f(x1b[m * 136 + n0]);
            out[(size_t)p * C + n1] = a1[r] + b1s + bs2f(x1b[m * 136 + n1]);
        }
    }
}

extern "C" void kernel_launch(void* const* d_in, const int* in_sizes, int n_in,
                              void* d_out, int out_size, void* d_ws, size_t ws_size,
                              hipStream_t stream) {
    const float* x      = (const float*)d_in[0];
    const float* y      = (const float*)d_in[1];
    const float* qv_w   = (const float*)d_in[2];
    const float* qv_b   = (const float*)d_in[3];
    const float* k_w    = (const float*)d_in[4];
    const float* k_b    = (const float*)d_in[5];
    const float* rpb    = (const float*)d_in[6];
    const float* proj_w = (const float*)d_in[7];
    const float* proj_b = (const float*)d_in[8];
    const float* n1_w   = (const float*)d_in[9];
    const float* n1_b   = (const float*)d_in[10];
    const float* n2_w   = (const float*)d_in[11];
    const float* n2_b   = (const float*)d_in[12];
    const float* fc1_w  = (const float*)d_in[13];
    const float* fc1_b  = (const float*)d_in[14];
    const float* fc2_w  = (const float*)d_in[15];
    const float* fc2_b  = (const float*)d_in[16];
    float* out = (float*)d_out;

    bf16* qb  = (bf16*)d_ws;
    bf16* vb  = qb + (size_t)N_PIX * C;
    bf16* kb  = vb + (size_t)N_PIX * C;
    short* wqv  = (short*)(kb + (size_t)N_PIX * C); // 32768
    short* wk   = wqv + 32768;                      // 16384
    short* wproj= wk + 16384;                       // 16384
    short* wfc1 = wproj + 16384;                    // 65536
    short* wfc2 = wfc1 + 65536;                     // 65536  (total ~12.4 MB)

    k_wconv<<<256, 256, 0, stream>>>(qv_w, k_w, proj_w, fc1_w, fc2_w,
                                     wqv, wk, wproj, wfc1, wfc2);
    k_qkv<<<256, 512, 0, stream>>>(x, y, wqv, qv_b, wk, k_b, n1_w, n1_b, qb, vb, kb);
    k_fam<<<512, 512, 0, stream>>>(qb, kb, vb, rpb, x, wproj, proj_b, n2_w, n2_b,
                                   wfc1, fc1_b, wfc2, fc2_b, out);
}

// Round 16
// 161.594 us; speedup vs baseline: 1.0883x; 1.0264x over previous
//
#include <hip/hip_runtime.h>
#include <hip/hip_bf16.h>

// CrossNATBlock2D: B=1, H=W=128, C=128, HEADS=4, HD=32, K=7  (fp32 I/O)
// R16: R14 structure (best passing). Changes: (1) k_qkv also emits xb = bf16(x)
// so k_fam's residual reads 4MB bf16 instead of 8MB fp32 from cold HBM;
// (2) k_fam hoists aQ + residual loads to kernel top (HBM latency overlaps
// LDS staging); (3) k_qkv at 32 px/block (512 blocks, ~4 blocks/CU).

#define N_PIX 16384
#define C 128
#define HEADS 4
#define HD 32
#define HW 128

typedef __hip_bfloat16 bf16;
typedef __attribute__((ext_vector_type(8))) short bf16x8;
typedef __attribute__((ext_vector_type(4))) float f32x4;

__device__ __forceinline__ short f2bs(float f) {
    bf16 h = __float2bfloat16(f);
    return (short)__bfloat16_as_ushort(h);
}
__device__ __forceinline__ float bs2f(short s) {
    __hip_bfloat16_raw r; r.x = (unsigned short)s;
    return __bfloat162float(__hip_bfloat16(r));
}
__device__ __forceinline__ float gelu_f(float v) {
    const float z = 1.5957691216f * (v + 0.044715f * v * v * v);
    return v / (1.f + __expf(-z));
}

// ---------- kernel 0: convert weights fp32 -> bf16 into ws ----------
__global__ __launch_bounds__(256) void k_wconv(
    const float* __restrict__ qv_w, const float* __restrict__ k_w,
    const float* __restrict__ proj_w, const float* __restrict__ fc1_w,
    const float* __restrict__ fc2_w,
    short* __restrict__ wqv, short* __restrict__ wk, short* __restrict__ wproj,
    short* __restrict__ wfc1, short* __restrict__ wfc2) {
    const int i = blockIdx.x * 256 + threadIdx.x;
    if (i < 32768) wqv[i] = f2bs(qv_w[i]);
    if (i < 16384) { wk[i] = f2bs(k_w[i]); wproj[i] = f2bs(proj_w[i]); }
    if (i < 65536) { wfc1[i] = f2bs(fc1_w[i]); wfc2[i] = f2bs(fc2_w[i]); }
}

// ---------- kernel 1: LN1 + QV GEMM + K proj + xb emit, 32 px/block ----------
// swizzle: block b -> pixels (b&7)*2048 + (b>>3)*32
__global__ __launch_bounds__(512, 6) void k_qkv(
    const float* __restrict__ x, const float* __restrict__ y,
    const short* __restrict__ wqv, const float* __restrict__ qv_b,
    const short* __restrict__ wk, const float* __restrict__ k_b,
    const float* __restrict__ n1_w, const float* __restrict__ n1_b,
    bf16* __restrict__ qb, bf16* __restrict__ vb, bf16* __restrict__ kb,
    bf16* __restrict__ xbo) {
    __shared__ float xr[32][132];
    __shared__ short xn[32][136];
    __shared__ short yb[32][136];
    __shared__ float muA[32], riA[32];
    const int t = threadIdx.x;
    const int pix0 = (blockIdx.x & 7) * 2048 + (blockIdx.x >> 3) * 32;
    for (int e = t; e < 32 * 128; e += 512) {
        const int r = e >> 7, c = e & 127;
        const float v = x[(pix0 + r) * C + c];
        xr[r][c] = v;
        xbo[(pix0 + r) * C + c] = __float2bfloat16(v);
        yb[r][c] = f2bs(y[(pix0 + r) * C + c]);
    }
    __syncthreads();
    if (t < 256) {
        const int r = t >> 3, s = t & 7;
        float sm = 0.f, sq = 0.f;
        for (int i = 0; i < 16; i++) { float v = xr[r][s * 16 + i]; sm += v; sq += v * v; }
        for (int m = 1; m < 8; m <<= 1) { sm += __shfl_xor(sm, m, 64); sq += __shfl_xor(sq, m, 64); }
        if (s == 0) {
            const float mu = sm * (1.f / 128.f);
            const float var = sq * (1.f / 128.f) - mu * mu;
            muA[r] = mu; riA[r] = rsqrtf(var + 1e-5f);
        }
    }
    __syncthreads();
    for (int e = t; e < 32 * 128; e += 512) {
        const int r = e >> 7, c = e & 127;
        xn[r][c] = f2bs((xr[r][c] - muA[r]) * riA[r] * n1_w[c] + n1_b[c]);
    }
    __syncthreads();
    const int wave = t >> 6, lane = t & 63, quad = lane >> 4, l15 = lane & 15;
    const int mt = wave & 1, wv = wave >> 1;
    const float scale = 0.1767766952966369f;   // 1/sqrt(32)
    // qv GEMM: A preloaded once, 4 n-tiles per wave
    {
        bf16x8 aA[4];
#pragma unroll
        for (int kt = 0; kt < 4; kt++)
            aA[kt] = *(const bf16x8*)&xn[mt * 16 + l15][kt * 32 + quad * 8];
#pragma unroll
        for (int s = 0; s < 4; s++) {
            const int n = (wv * 4 + s) * 16 + l15;
            f32x4 acc = {0.f, 0.f, 0.f, 0.f};
#pragma unroll
            for (int kt = 0; kt < 4; kt++) {
                bf16x8 b = *(const bf16x8*)&wqv[n * C + kt * 32 + quad * 8];
                acc = __builtin_amdgcn_mfma_f32_16x16x32_bf16(aA[kt], b, acc, 0, 0, 0);
            }
            const float bias = qv_b[n];
#pragma unroll
            for (int r = 0; r < 4; r++) {
                const int m = mt * 16 + quad * 4 + r;
                const float v = acc[r] + bias;
                if (n < C) qb[(pix0 + m) * C + n] = __float2bfloat16(v * scale);
                else       vb[(pix0 + m) * C + (n - C)] = __float2bfloat16(v);
            }
        }
    }
    // k GEMM: A preloaded, 2 n-tiles, interleaved accumulators
    {
        bf16x8 aY[4];
#pragma unroll
        for (int kt = 0; kt < 4; kt++)
            aY[kt] = *(const bf16x8*)&yb[mt * 16 + l15][kt * 32 + quad * 8];
        const int n0 = (wv * 2) * 16 + l15, n1 = (wv * 2 + 1) * 16 + l15;
        f32x4 a0 = {0.f, 0.f, 0.f, 0.f}, a1 = {0.f, 0.f, 0.f, 0.f};
#pragma unroll
        for (int kt = 0; kt < 4; kt++) {
            bf16x8 b0 = *(const bf16x8*)&wk[n0 * C + kt * 32 + quad * 8];
            bf16x8 b1 = *(const bf16x8*)&wk[n1 * C + kt * 32 + quad * 8];
            a0 = __builtin_amdgcn_mfma_f32_16x16x32_bf16(aY[kt], b0, a0, 0, 0, 0);
            a1 = __builtin_amdgcn_mfma_f32_16x16x32_bf16(aY[kt], b1, a1, 0, 0, 0);
        }
        const float b0s = k_b[n0], b1s = k_b[n1];
#pragma unroll
        for (int r = 0; r < 4; r++) {
            const int m = mt * 16 + quad * 4 + r;
            kb[(pix0 + m) * C + n0] = __float2bfloat16(a0[r] + b0s);
            kb[(pix0 + m) * C + n1] = __float2bfloat16(a1[r] + b1s);
        }
    }
}

// ---------- kernel 2: fused attention + proj + residual + LN2 + MLP ----------
// 8x4 tile (32 px), 512 thr; wave = (mt<<2)|head. Union 14x10 = 140 rows.
// swizzle: b&7 = XCD band; tile_i = (b&7)*2 + ((b>>3)>>5), tile_j = (b>>3)&31.
// aQ + residual (xb) values prefetched into registers before LDS staging.
__global__ __launch_bounds__(512, 2) void k_fam(
    const bf16* __restrict__ qb, const bf16* __restrict__ kb,
    const bf16* __restrict__ vb, const float* __restrict__ rpb,
    const bf16* __restrict__ xb,
    const short* __restrict__ wproj, const float* __restrict__ proj_b,
    const float* __restrict__ n2_w, const float* __restrict__ n2_b,
    const short* __restrict__ wfc1, const float* __restrict__ fc1_b,
    const short* __restrict__ wfc2, const float* __restrict__ fc2_b,
    float* __restrict__ out) {
    __shared__ short KP[19008];   // K 140x132 -> P 128x144
    __shared__ short Vl[19008];   // V 140x132 -> hb
    __shared__ float muA[32], riA[32];
    short* const Pm  = KP;            // 128 x 144
    short* const aoL = KP;            // 32 x 136 (after PV)
    short* const x1b = KP + 4352;     // 32 x 136
    short* const xnb = KP + 8704;     // 32 x 136
    short* const hb  = Vl;            // 32 x 520
    const int t = threadIdx.x;
    const int wave = t >> 6, lane = t & 63, quad = lane >> 4, l15 = lane & 15;
    const int h = wave & 3, mt = wave >> 2;
    const int s_ = blockIdx.x >> 3;
    const int i0 = ((blockIdx.x & 7) * 2 + (s_ >> 5)) * 8;
    const int j0 = (s_ & 31) * 4;
    const int rs = min(max(i0 - 3, 0), 114);
    const int cs = min(max(j0 - 3, 0), 118);
    // ---- register prefetch (HBM latency overlaps staging below) ----
    const int mA = mt * 16 + l15;
    const int pA = (i0 + (mA >> 2)) * HW + j0 + (mA & 3);
    const bf16x8 aQ = *(const bf16x8*)(qb + (size_t)pA * C + h * HD + quad * 8);
    const int nR0 = h * 16 + l15, nR1 = (h + 4) * 16 + l15;
    short xres0[4], xres1[4];
#pragma unroll
    for (int r = 0; r < 4; r++) {
        const int m = mt * 16 + quad * 4 + r;
        const int p = (i0 + (m >> 2)) * HW + j0 + (m & 3);
        xres0[r] = *(const short*)(xb + (size_t)p * C + nR0);
        xres1[r] = *(const short*)(xb + (size_t)p * C + nR1);
    }
    // ---- phase 1: stage K,V unions (140 rows x 128 ch) ----
    for (int u = t; u < 140 * 16 * 2; u += 512) {
        const int tv = (u >= 2240) ? 1 : 0;
        const int uu = tv ? u - 2240 : u;
        const int r = uu >> 4, seg = uu & 15;
        const size_t g = (size_t)((rs + r / 10) * HW + cs + r % 10) * C + seg * 8;
        const uint4 d = *(const uint4*)((tv ? vb : kb) + g);
        *(uint4*)&(tv ? Vl : KP)[r * 132 + seg * 8] = d;
    }
    __syncthreads();
    // ---- phase 2: QK^T + bias/mask + softmax ----
    f32x4 S[9];
#pragma unroll
    for (int nt = 0; nt < 9; nt++) {
        const bf16x8 bK = *(const bf16x8*)&KP[(nt * 16 + l15) * 132 + h * HD + quad * 8];
        f32x4 z = {0.f, 0.f, 0.f, 0.f};
        S[nt] = __builtin_amdgcn_mfma_f32_16x16x32_bf16(aQ, bK, z, 0, 0, 0);
    }
    const float* rpbh = rpb + h * 169;
    float smx[4];
#pragma unroll
    for (int r = 0; r < 4; r++) {
        const int m = mt * 16 + quad * 4 + r;
        const int i = i0 + (m >> 2), j = j0 + (m & 3);
        const int shi = min(max(i - 3, 0), 121);
        const int swj = min(max(j - 3, 0), 121);
        float best = -1e30f;
#pragma unroll
        for (int nt = 0; nt < 9; nt++) {
            const int nb = nt * 16 + l15;
            const int ai = rs + nb / 10, aj = cs + nb % 10;
            const bool valid = (nb < 140) & (ai >= shi) & (ai <= shi + 6) & (aj >= swj) & (aj <= swj + 6);
            const int ri = min(max(ai - i + 6, 0), 12);
            const int rj = min(max(aj - j + 6, 0), 12);
            const float v = valid ? (S[nt][r] + rpbh[ri * 13 + rj]) : -1e30f;
            S[nt][r] = v;
            best = fmaxf(best, v);
        }
        for (int msk = 1; msk < 16; msk <<= 1) best = fmaxf(best, __shfl_xor(best, msk, 64));
        float s = 0.f;
#pragma unroll
        for (int nt = 0; nt < 9; nt++) {
            const float e = __expf(S[nt][r] - best);
            S[nt][r] = e;
            s += e;
        }
        for (int msk = 1; msk < 16; msk <<= 1) s += __shfl_xor(s, msk, 64);
        smx[r] = 1.f / s;
    }
    __syncthreads();   // all K reads done
    // ---- phase 3: P -> Pm (stride 144) ----
#pragma unroll
    for (int r = 0; r < 4; r++) {
        short* prow = &Pm[(wave * 16 + quad * 4 + r) * 144];
#pragma unroll
        for (int nt = 0; nt < 9; nt++)
            prow[nt * 16 + l15] = f2bs(S[nt][r] * smx[r]);
    }
    __syncthreads();
    // ---- phase 4: PV ----
    f32x4 O0 = {0.f, 0.f, 0.f, 0.f}, O1 = {0.f, 0.f, 0.f, 0.f};
#pragma unroll
    for (int kt = 0; kt < 5; kt++) {
        const bf16x8 aP = *(const bf16x8*)&Pm[(wave * 16 + l15) * 144 + kt * 32 + quad * 8];
#pragma unroll
        for (int nt2 = 0; nt2 < 2; nt2++) {
            bf16x8 bV;
            const int ch = h * HD + nt2 * 16 + l15;
#pragma unroll
            for (int jj = 0; jj < 8; jj++) {
                const int nbr = kt * 32 + quad * 8 + jj;
                bV[jj] = (nbr < 140) ? Vl[nbr * 132 + ch] : (short)0;
            }
            if (nt2 == 0) O0 = __builtin_amdgcn_mfma_f32_16x16x32_bf16(aP, bV, O0, 0, 0, 0);
            else          O1 = __builtin_amdgcn_mfma_f32_16x16x32_bf16(aP, bV, O1, 0, 0, 0);
        }
    }
    __syncthreads();   // all P/V reads done; K/V regions now dead
    // ---- phase 5: ao -> aoL ----
#pragma unroll
    for (int r = 0; r < 4; r++) {
        const int m = mt * 16 + quad * 4 + r;
        aoL[m * 136 + h * HD + l15] = f2bs(O0[r]);
        aoL[m * 136 + h * HD + 16 + l15] = f2bs(O1[r]);
    }
    __syncthreads();
    // ---- phase 6: proj + residual (prefetched xb) -> x1b ----
    {
        bf16x8 aO[4];
#pragma unroll
        for (int kt = 0; kt < 4; kt++)
            aO[kt] = *(const bf16x8*)&aoL[(mt * 16 + l15) * 136 + kt * 32 + quad * 8];
        f32x4 a0 = {0.f, 0.f, 0.f, 0.f}, a1 = {0.f, 0.f, 0.f, 0.f};
#pragma unroll
        for (int kt = 0; kt < 4; kt++) {
            bf16x8 b0 = *(const bf16x8*)&wproj[nR0 * C + kt * 32 + quad * 8];
            bf16x8 b1 = *(const bf16x8*)&wproj[nR1 * C + kt * 32 + quad * 8];
            a0 = __builtin_amdgcn_mfma_f32_16x16x32_bf16(aO[kt], b0, a0, 0, 0, 0);
            a1 = __builtin_amdgcn_mfma_f32_16x16x32_bf16(aO[kt], b1, a1, 0, 0, 0);
        }
        const float b0s = proj_b[nR0], b1s = proj_b[nR1];
#pragma unroll
        for (int r = 0; r < 4; r++) {
            const int m = mt * 16 + quad * 4 + r;
            x1b[m * 136 + nR0] = f2bs(bs2f(xres0[r]) + a0[r] + b0s);
            x1b[m * 136 + nR1] = f2bs(bs2f(xres1[r]) + a1[r] + b1s);
        }
    }
    __syncthreads();
    // ---- phase 7: LN2 stats ----
    if (t < 256) {
        const int r = t >> 3, s = t & 7;
        float sm = 0.f, sq = 0.f;
        for (int i = 0; i < 16; i++) { float v = bs2f(x1b[r * 136 + s * 16 + i]); sm += v; sq += v * v; }
        for (int m = 1; m < 8; m <<= 1) { sm += __shfl_xor(sm, m, 64); sq += __shfl_xor(sq, m, 64); }
        if (s == 0) {
            const float mu = sm * (1.f / 128.f);
            const float var = sq * (1.f / 128.f) - mu * mu;
            muA[r] = mu; riA[r] = rsqrtf(var + 1e-5f);
        }
    }
    __syncthreads();
    // ---- phase 8: xn = LN(x1) -> xnb ----
    for (int e = t; e < 32 * 128; e += 512) {
        const int r = e >> 7, c = e & 127;
        xnb[r * 136 + c] = f2bs((bs2f(x1b[r * 136 + c]) - muA[r]) * riA[r] * n2_w[c] + n2_b[c]);
    }
    __syncthreads();
    // ---- phase 9: fc1 + gelu -> hb ----
    {
        bf16x8 aX[4];
#pragma unroll
        for (int kt = 0; kt < 4; kt++)
            aX[kt] = *(const bf16x8*)&xnb[(mt * 16 + l15) * 136 + kt * 32 + quad * 8];
#pragma unroll
        for (int a = 0; a < 4; a++) {
            const int n0 = (h + 8 * a) * 16 + l15, n1 = (h + 8 * a + 4) * 16 + l15;
            f32x4 a0 = {0.f, 0.f, 0.f, 0.f}, a1 = {0.f, 0.f, 0.f, 0.f};
#pragma unroll
            for (int kt = 0; kt < 4; kt++) {
                bf16x8 b0 = *(const bf16x8*)&wfc1[n0 * C + kt * 32 + quad * 8];
                bf16x8 b1 = *(const bf16x8*)&wfc1[n1 * C + kt * 32 + quad * 8];
                a0 = __builtin_amdgcn_mfma_f32_16x16x32_bf16(aX[kt], b0, a0, 0, 0, 0);
                a1 = __builtin_amdgcn_mfma_f32_16x16x32_bf16(aX[kt], b1, a1, 0, 0, 0);
            }
            const float b0s = fc1_b[n0], b1s = fc1_b[n1];
#pragma unroll
            for (int r = 0; r < 4; r++) {
                const int m = mt * 16 + quad * 4 + r;
                hb[m * 520 + n0] = f2bs(gelu_f(a0[r] + b0s));
                hb[m * 520 + n1] = f2bs(gelu_f(a1[r] + b1s));
            }
        }
    }
    __syncthreads();
    // ---- phase 10: fc2 + residual -> out ----
    {
        f32x4 a0 = {0.f, 0.f, 0.f, 0.f}, a1 = {0.f, 0.f, 0.f, 0.f};
#pragma unroll
        for (int kt = 0; kt < 16; kt++) {
            const bf16x8 aP = *(const bf16x8*)&hb[(mt * 16 + l15) * 520 + kt * 32 + quad * 8];
            bf16x8 b0 = *(const bf16x8*)&wfc2[nR0 * 512 + kt * 32 + quad * 8];
            bf16x8 b1 = *(const bf16x8*)&wfc2[nR1 * 512 + kt * 32 + quad * 8];
            a0 = __builtin_amdgcn_mfma_f32_16x16x32_bf16(aP, b0, a0, 0, 0, 0);
            a1 = __builtin_amdgcn_mfma_f32_16x16x32_bf16(aP, b1, a1, 0, 0, 0);
        }
        const float b0s = fc2_b[nR0], b1s = fc2_b[nR1];
#pragma unroll
        for (int r = 0; r < 4; r++) {
            const int m = mt * 16 + quad * 4 + r;
            const int p = (i0 + (m >> 2)) * HW + j0 + (m & 3);
            out[(size_t)p * C + nR0] = a0[r] + b0s + bs2f(x1b[m * 136 + nR0]);
            out[(size_t)p * C + nR1] = a1[r] + b1s + bs2f(x1b[m * 136 + nR1]);
        }
    }
}

extern "C" void kernel_launch(void* const* d_in, const int* in_sizes, int n_in,
                              void* d_out, int out_size, void* d_ws, size_t ws_size,
                              hipStream_t stream) {
    const float* x      = (const float*)d_in[0];
    const float* y      = (const float*)d_in[1];
    const float* qv_w   = (const float*)d_in[2];
    const float* qv_b   = (const float*)d_in[3];
    const float* k_w    = (const float*)d_in[4];
    const float* k_b    = (const float*)d_in[5];
    const float* rpb    = (const float*)d_in[6];
    const float* proj_w = (const float*)d_in[7];
    const float* proj_b = (const float*)d_in[8];
    const float* n1_w   = (const float*)d_in[9];
    const float* n1_b   = (const float*)d_in[10];
    const float* n2_w   = (const float*)d_in[11];
    const float* n2_b   = (const float*)d_in[12];
    const float* fc1_w  = (const float*)d_in[13];
    const float* fc1_b  = (const float*)d_in[14];
    const float* fc2_w  = (const float*)d_in[15];
    const float* fc2_b  = (const float*)d_in[16];
    float* out = (float*)d_out;

    bf16* qb  = (bf16*)d_ws;
    bf16* vb  = qb + (size_t)N_PIX * C;
    bf16* kb  = vb + (size_t)N_PIX * C;
    bf16* xb  = kb + (size_t)N_PIX * C;             // bf16 copy of x (4 MB)
    short* wqv  = (short*)(xb + (size_t)N_PIX * C); // 32768
    short* wk   = wqv + 32768;                      // 16384
    short* wproj= wk + 16384;                       // 16384
    short* wfc1 = wproj + 16384;                    // 65536
    short* wfc2 = wfc1 + 65536;                     // 65536  (total ~16.4 MB)

    k_wconv<<<256, 256, 0, stream>>>(qv_w, k_w, proj_w, fc1_w, fc2_w,
                                     wqv, wk, wproj, wfc1, wfc2);
    k_qkv<<<512, 512, 0, stream>>>(x, y, wqv, qv_b, wk, k_b, n1_w, n1_b,
                                   qb, vb, kb, xb);
    k_fam<<<512, 512, 0, stream>>>(qb, kb, vb, rpb, xb, wproj, proj_b, n2_w, n2_b,
                                   wfc1, fc1_b, wfc2, fc2_b, out);
}

// Round 17
// 161.163 us; speedup vs baseline: 1.0912x; 1.0027x over previous
//
#include <hip/hip_runtime.h>
#include <hip/hip_bf16.h>

// CrossNATBlock2D: B=1, H=W=128, C=128, HEADS=4, HD=32, K=7  (fp32 I/O)
// R17: R16 structure. (1) PV bV gather de-predicated (kt<=3 always valid;
// kt=4 peeled); (2) removed P-write->PV barrier (same-wave rows only);
// (3) k_qkv staging vectorized (float4 loads, packed uint2 bf16 stores).

#define N_PIX 16384
#define C 128
#define HEADS 4
#define HD 32
#define HW 128

typedef __hip_bfloat16 bf16;
typedef __attribute__((ext_vector_type(8))) short bf16x8;
typedef __attribute__((ext_vector_type(4))) float f32x4;

__device__ __forceinline__ short f2bs(float f) {
    bf16 h = __float2bfloat16(f);
    return (short)__bfloat16_as_ushort(h);
}
__device__ __forceinline__ float bs2f(short s) {
    __hip_bfloat16_raw r; r.x = (unsigned short)s;
    return __bfloat162float(__hip_bfloat16(r));
}
__device__ __forceinline__ float gelu_f(float v) {
    const float z = 1.5957691216f * (v + 0.044715f * v * v * v);
    return v / (1.f + __expf(-z));
}
__device__ __forceinline__ unsigned int pack2(float a, float b) {
    return (unsigned int)(unsigned short)f2bs(a) |
           ((unsigned int)(unsigned short)f2bs(b) << 16);
}

// ---------- kernel 0: convert weights fp32 -> bf16 into ws ----------
__global__ __launch_bounds__(256) void k_wconv(
    const float* __restrict__ qv_w, const float* __restrict__ k_w,
    const float* __restrict__ proj_w, const float* __restrict__ fc1_w,
    const float* __restrict__ fc2_w,
    short* __restrict__ wqv, short* __restrict__ wk, short* __restrict__ wproj,
    short* __restrict__ wfc1, short* __restrict__ wfc2) {
    const int i = blockIdx.x * 256 + threadIdx.x;
    if (i < 32768) wqv[i] = f2bs(qv_w[i]);
    if (i < 16384) { wk[i] = f2bs(k_w[i]); wproj[i] = f2bs(proj_w[i]); }
    if (i < 65536) { wfc1[i] = f2bs(fc1_w[i]); wfc2[i] = f2bs(fc2_w[i]); }
}

// ---------- kernel 1: LN1 + QV GEMM + K proj + xb emit, 32 px/block ----------
// swizzle: block b -> pixels (b&7)*2048 + (b>>3)*32
__global__ __launch_bounds__(512, 6) void k_qkv(
    const float* __restrict__ x, const float* __restrict__ y,
    const short* __restrict__ wqv, const float* __restrict__ qv_b,
    const short* __restrict__ wk, const float* __restrict__ k_b,
    const float* __restrict__ n1_w, const float* __restrict__ n1_b,
    bf16* __restrict__ qb, bf16* __restrict__ vb, bf16* __restrict__ kb,
    bf16* __restrict__ xbo) {
    __shared__ float xr[32][132];
    __shared__ short xn[32][136];
    __shared__ short yb[32][136];
    __shared__ float muA[32], riA[32];
    const int t = threadIdx.x;
    const int pix0 = (blockIdx.x & 7) * 2048 + (blockIdx.x >> 3) * 32;
    for (int e = t; e < 1024; e += 512) {       // 1024 float4-groups (32x128)
        const int r = e >> 5, c4 = (e & 31) * 4;
        const float4 xv = *(const float4*)(x + (size_t)(pix0 + r) * C + c4);
        *(float4*)&xr[r][c4] = xv;
        uint2 xp; xp.x = pack2(xv.x, xv.y); xp.y = pack2(xv.z, xv.w);
        *(uint2*)(xbo + (size_t)(pix0 + r) * C + c4) = xp;
        const float4 yv = *(const float4*)(y + (size_t)(pix0 + r) * C + c4);
        uint2 yp; yp.x = pack2(yv.x, yv.y); yp.y = pack2(yv.z, yv.w);
        *(uint2*)&yb[r][c4] = yp;
    }
    __syncthreads();
    if (t < 256) {
        const int r = t >> 3, s = t & 7;
        float sm = 0.f, sq = 0.f;
        for (int i = 0; i < 16; i++) { float v = xr[r][s * 16 + i]; sm += v; sq += v * v; }
        for (int m = 1; m < 8; m <<= 1) { sm += __shfl_xor(sm, m, 64); sq += __shfl_xor(sq, m, 64); }
        if (s == 0) {
            const float mu = sm * (1.f / 128.f);
            const float var = sq * (1.f / 128.f) - mu * mu;
            muA[r] = mu; riA[r] = rsqrtf(var + 1e-5f);
        }
    }
    __syncthreads();
    for (int e = t; e < 32 * 128; e += 512) {
        const int r = e >> 7, c = e & 127;
        xn[r][c] = f2bs((xr[r][c] - muA[r]) * riA[r] * n1_w[c] + n1_b[c]);
    }
    __syncthreads();
    const int wave = t >> 6, lane = t & 63, quad = lane >> 4, l15 = lane & 15;
    const int mt = wave & 1, wv = wave >> 1;
    const float scale = 0.1767766952966369f;   // 1/sqrt(32)
    // qv GEMM: A preloaded once, 4 n-tiles per wave
    {
        bf16x8 aA[4];
#pragma unroll
        for (int kt = 0; kt < 4; kt++)
            aA[kt] = *(const bf16x8*)&xn[mt * 16 + l15][kt * 32 + quad * 8];
#pragma unroll
        for (int s = 0; s < 4; s++) {
            const int n = (wv * 4 + s) * 16 + l15;
            f32x4 acc = {0.f, 0.f, 0.f, 0.f};
#pragma unroll
            for (int kt = 0; kt < 4; kt++) {
                bf16x8 b = *(const bf16x8*)&wqv[n * C + kt * 32 + quad * 8];
                acc = __builtin_amdgcn_mfma_f32_16x16x32_bf16(aA[kt], b, acc, 0, 0, 0);
            }
            const float bias = qv_b[n];
#pragma unroll
            for (int r = 0; r < 4; r++) {
                const int m = mt * 16 + quad * 4 + r;
                const float v = acc[r] + bias;
                if (n < C) qb[(pix0 + m) * C + n] = __float2bfloat16(v * scale);
                else       vb[(pix0 + m) * C + (n - C)] = __float2bfloat16(v);
            }
        }
    }
    // k GEMM: A preloaded, 2 n-tiles, interleaved accumulators
    {
        bf16x8 aY[4];
#pragma unroll
        for (int kt = 0; kt < 4; kt++)
            aY[kt] = *(const bf16x8*)&yb[mt * 16 + l15][kt * 32 + quad * 8];
        const int n0 = (wv * 2) * 16 + l15, n1 = (wv * 2 + 1) * 16 + l15;
        f32x4 a0 = {0.f, 0.f, 0.f, 0.f}, a1 = {0.f, 0.f, 0.f, 0.f};
#pragma unroll
        for (int kt = 0; kt < 4; kt++) {
            bf16x8 b0 = *(const bf16x8*)&wk[n0 * C + kt * 32 + quad * 8];
            bf16x8 b1 = *(const bf16x8*)&wk[n1 * C + kt * 32 + quad * 8];
            a0 = __builtin_amdgcn_mfma_f32_16x16x32_bf16(aY[kt], b0, a0, 0, 0, 0);
            a1 = __builtin_amdgcn_mfma_f32_16x16x32_bf16(aY[kt], b1, a1, 0, 0, 0);
        }
        const float b0s = k_b[n0], b1s = k_b[n1];
#pragma unroll
        for (int r = 0; r < 4; r++) {
            const int m = mt * 16 + quad * 4 + r;
            kb[(pix0 + m) * C + n0] = __float2bfloat16(a0[r] + b0s);
            kb[(pix0 + m) * C + n1] = __float2bfloat16(a1[r] + b1s);
        }
    }
}

// ---------- kernel 2: fused attention + proj + residual + LN2 + MLP ----------
// 8x4 tile (32 px), 512 thr; wave = (mt<<2)|head. Union 14x10 = 140 rows.
__global__ __launch_bounds__(512, 2) void k_fam(
    const bf16* __restrict__ qb, const bf16* __restrict__ kb,
    const bf16* __restrict__ vb, const float* __restrict__ rpb,
    const bf16* __restrict__ xb,
    const short* __restrict__ wproj, const float* __restrict__ proj_b,
    const float* __restrict__ n2_w, const float* __restrict__ n2_b,
    const short* __restrict__ wfc1, const float* __restrict__ fc1_b,
    const short* __restrict__ wfc2, const float* __restrict__ fc2_b,
    float* __restrict__ out) {
    __shared__ short KP[19008];   // K 140x132 -> P 128x144
    __shared__ short Vl[19008];   // V 140x132 -> hb
    __shared__ float muA[32], riA[32];
    short* const Pm  = KP;            // 128 x 144
    short* const aoL = KP;            // 32 x 136 (after PV)
    short* const x1b = KP + 4352;     // 32 x 136
    short* const xnb = KP + 8704;     // 32 x 136
    short* const hb  = Vl;            // 32 x 520
    const int t = threadIdx.x;
    const int wave = t >> 6, lane = t & 63, quad = lane >> 4, l15 = lane & 15;
    const int h = wave & 3, mt = wave >> 2;
    const int s_ = blockIdx.x >> 3;
    const int i0 = ((blockIdx.x & 7) * 2 + (s_ >> 5)) * 8;
    const int j0 = (s_ & 31) * 4;
    const int rs = min(max(i0 - 3, 0), 114);
    const int cs = min(max(j0 - 3, 0), 118);
    // ---- register prefetch (HBM latency overlaps staging below) ----
    const int mA = mt * 16 + l15;
    const int pA = (i0 + (mA >> 2)) * HW + j0 + (mA & 3);
    const bf16x8 aQ = *(const bf16x8*)(qb + (size_t)pA * C + h * HD + quad * 8);
    const int nR0 = h * 16 + l15, nR1 = (h + 4) * 16 + l15;
    short xres0[4], xres1[4];
#pragma unroll
    for (int r = 0; r < 4; r++) {
        const int m = mt * 16 + quad * 4 + r;
        const int p = (i0 + (m >> 2)) * HW + j0 + (m & 3);
        xres0[r] = *(const short*)(xb + (size_t)p * C + nR0);
        xres1[r] = *(const short*)(xb + (size_t)p * C + nR1);
    }
    // ---- phase 1: stage K,V unions (140 rows x 128 ch) ----
    for (int u = t; u < 140 * 16 * 2; u += 512) {
        const int tv = (u >= 2240) ? 1 : 0;
        const int uu = tv ? u - 2240 : u;
        const int r = uu >> 4, seg = uu & 15;
        const size_t g = (size_t)((rs + r / 10) * HW + cs + r % 10) * C + seg * 8;
        const uint4 d = *(const uint4*)((tv ? vb : kb) + g);
        *(uint4*)&(tv ? Vl : KP)[r * 132 + seg * 8] = d;
    }
    __syncthreads();
    // ---- phase 2: QK^T + bias/mask + softmax ----
    f32x4 S[9];
#pragma unroll
    for (int nt = 0; nt < 9; nt++) {
        const bf16x8 bK = *(const bf16x8*)&KP[(nt * 16 + l15) * 132 + h * HD + quad * 8];
        f32x4 z = {0.f, 0.f, 0.f, 0.f};
        S[nt] = __builtin_amdgcn_mfma_f32_16x16x32_bf16(aQ, bK, z, 0, 0, 0);
    }
    const float* rpbh = rpb + h * 169;
    float smx[4];
#pragma unroll
    for (int r = 0; r < 4; r++) {
        const int m = mt * 16 + quad * 4 + r;
        const int i = i0 + (m >> 2), j = j0 + (m & 3);
        const int shi = min(max(i - 3, 0), 121);
        const int swj = min(max(j - 3, 0), 121);
        float best = -1e30f;
#pragma unroll
        for (int nt = 0; nt < 9; nt++) {
            const int nb = nt * 16 + l15;
            const int ai = rs + nb / 10, aj = cs + nb % 10;
            const bool valid = (nb < 140) & (ai >= shi) & (ai <= shi + 6) & (aj >= swj) & (aj <= swj + 6);
            const int ri = min(max(ai - i + 6, 0), 12);
            const int rj = min(max(aj - j + 6, 0), 12);
            const float v = valid ? (S[nt][r] + rpbh[ri * 13 + rj]) : -1e30f;
            S[nt][r] = v;
            best = fmaxf(best, v);
        }
        for (int msk = 1; msk < 16; msk <<= 1) best = fmaxf(best, __shfl_xor(best, msk, 64));
        float s = 0.f;
#pragma unroll
        for (int nt = 0; nt < 9; nt++) {
            const float e = __expf(S[nt][r] - best);
            S[nt][r] = e;
            s += e;
        }
        for (int msk = 1; msk < 16; msk <<= 1) s += __shfl_xor(s, msk, 64);
        smx[r] = 1.f / s;
    }
    __syncthreads();   // all K reads done before P overwrites
    // ---- phase 3: P -> Pm (stride 144, own rows) ----
#pragma unroll
    for (int r = 0; r < 4; r++) {
        short* prow = &Pm[(wave * 16 + quad * 4 + r) * 144];
#pragma unroll
        for (int nt = 0; nt < 9; nt++)
            prow[nt * 16 + l15] = f2bs(S[nt][r] * smx[r]);
    }
    // NOTE: no barrier — PV reads only this wave's own 16 P rows (lgkmcnt
    // ordering within the wave is sufficient).
    // ---- phase 4: PV (kt 0..3 unpredicated; kt=4 peeled) ----
    f32x4 O0 = {0.f, 0.f, 0.f, 0.f}, O1 = {0.f, 0.f, 0.f, 0.f};
#pragma unroll
    for (int kt = 0; kt < 4; kt++) {
        const bf16x8 aP = *(const bf16x8*)&Pm[(wave * 16 + l15) * 144 + kt * 32 + quad * 8];
#pragma unroll
        for (int nt2 = 0; nt2 < 2; nt2++) {
            const int ch = h * HD + nt2 * 16 + l15;
            const int base = (kt * 32 + quad * 8) * 132 + ch;
            bf16x8 bV;
#pragma unroll
            for (int jj = 0; jj < 8; jj++) bV[jj] = Vl[base + jj * 132];
            if (nt2 == 0) O0 = __builtin_amdgcn_mfma_f32_16x16x32_bf16(aP, bV, O0, 0, 0, 0);
            else          O1 = __builtin_amdgcn_mfma_f32_16x16x32_bf16(aP, bV, O1, 0, 0, 0);
        }
    }
    {   // kt = 4: nbr 128..159; valid only 128..139
        const bf16x8 aP = *(const bf16x8*)&Pm[(wave * 16 + l15) * 144 + 128 + quad * 8];
#pragma unroll
        for (int nt2 = 0; nt2 < 2; nt2++) {
            const int ch = h * HD + nt2 * 16 + l15;
            bf16x8 bV = {0, 0, 0, 0, 0, 0, 0, 0};
            if (quad == 0) {
                const int base = 128 * 132 + ch;
#pragma unroll
                for (int jj = 0; jj < 8; jj++) bV[jj] = Vl[base + jj * 132];
            } else if (quad == 1) {
                const int base = 136 * 132 + ch;
#pragma unroll
                for (int jj = 0; jj < 4; jj++) bV[jj] = Vl[base + jj * 132];
            }
            if (nt2 == 0) O0 = __builtin_amdgcn_mfma_f32_16x16x32_bf16(aP, bV, O0, 0, 0, 0);
            else          O1 = __builtin_amdgcn_mfma_f32_16x16x32_bf16(aP, bV, O1, 0, 0, 0);
        }
    }
    __syncthreads();   // all P/V reads done; K/V regions now dead
    // ---- phase 5: ao -> aoL ----
#pragma unroll
    for (int r = 0; r < 4; r++) {
        const int m = mt * 16 + quad * 4 + r;
        aoL[m * 136 + h * HD + l15] = f2bs(O0[r]);
        aoL[m * 136 + h * HD + 16 + l15] = f2bs(O1[r]);
    }
    __syncthreads();
    // ---- phase 6: proj + residual (prefetched xb) -> x1b ----
    {
        bf16x8 aO[4];
#pragma unroll
        for (int kt = 0; kt < 4; kt++)
            aO[kt] = *(const bf16x8*)&aoL[(mt * 16 + l15) * 136 + kt * 32 + quad * 8];
        f32x4 a0 = {0.f, 0.f, 0.f, 0.f}, a1 = {0.f, 0.f, 0.f, 0.f};
#pragma unroll
        for (int kt = 0; kt < 4; kt++) {
            bf16x8 b0 = *(const bf16x8*)&wproj[nR0 * C + kt * 32 + quad * 8];
            bf16x8 b1 = *(const bf16x8*)&wproj[nR1 * C + kt * 32 + quad * 8];
            a0 = __builtin_amdgcn_mfma_f32_16x16x32_bf16(aO[kt], b0, a0, 0, 0, 0);
            a1 = __builtin_amdgcn_mfma_f32_16x16x32_bf16(aO[kt], b1, a1, 0, 0, 0);
        }
        const float b0s = proj_b[nR0], b1s = proj_b[nR1];
#pragma unroll
        for (int r = 0; r < 4; r++) {
            const int m = mt * 16 + quad * 4 + r;
            x1b[m * 136 + nR0] = f2bs(bs2f(xres0[r]) + a0[r] + b0s);
            x1b[m * 136 + nR1] = f2bs(bs2f(xres1[r]) + a1[r] + b1s);
        }
    }
    __syncthreads();
    // ---- phase 7: LN2 stats ----
    if (t < 256) {
        const int r = t >> 3, s = t & 7;
        float sm = 0.f, sq = 0.f;
        for (int i = 0; i < 16; i++) { float v = bs2f(x1b[r * 136 + s * 16 + i]); sm += v; sq += v * v; }
        for (int m = 1; m < 8; m <<= 1) { sm += __shfl_xor(sm, m, 64); sq += __shfl_xor(sq, m, 64); }
        if (s == 0) {
            const float mu = sm * (1.f / 128.f);
            const float var = sq * (1.f / 128.f) - mu * mu;
            muA[r] = mu; riA[r] = rsqrtf(var + 1e-5f);
        }
    }
    __syncthreads();
    // ---- phase 8: xn = LN(x1) -> xnb ----
    for (int e = t; e < 32 * 128; e += 512) {
        const int r = e >> 7, c = e & 127;
        xnb[r * 136 + c] = f2bs((bs2f(x1b[r * 136 + c]) - muA[r]) * riA[r] * n2_w[c] + n2_b[c]);
    }
    __syncthreads();
    // ---- phase 9: fc1 + gelu -> hb ----
    {
        bf16x8 aX[4];
#pragma unroll
        for (int kt = 0; kt < 4; kt++)
            aX[kt] = *(const bf16x8*)&xnb[(mt * 16 + l15) * 136 + kt * 32 + quad * 8];
#pragma unroll
        for (int a = 0; a < 4; a++) {
            const int n0 = (h + 8 * a) * 16 + l15, n1 = (h + 8 * a + 4) * 16 + l15;
            f32x4 a0 = {0.f, 0.f, 0.f, 0.f}, a1 = {0.f, 0.f, 0.f, 0.f};
#pragma unroll
            for (int kt = 0; kt < 4; kt++) {
                bf16x8 b0 = *(const bf16x8*)&wfc1[n0 * C + kt * 32 + quad * 8];
                bf16x8 b1 = *(const bf16x8*)&wfc1[n1 * C + kt * 32 + quad * 8];
                a0 = __builtin_amdgcn_mfma_f32_16x16x32_bf16(aX[kt], b0, a0, 0, 0, 0);
                a1 = __builtin_amdgcn_mfma_f32_16x16x32_bf16(aX[kt], b1, a1, 0, 0, 0);
            }
            const float b0s = fc1_b[n0], b1s = fc1_b[n1];
#pragma unroll
            for (int r = 0; r < 4; r++) {
                const int m = mt * 16 + quad * 4 + r;
                hb[m * 520 + n0] = f2bs(gelu_f(a0[r] + b0s));
                hb[m * 520 + n1] = f2bs(gelu_f(a1[r] + b1s));
            }
        }
    }
    __syncthreads();
    // ---- phase 10: fc2 + residual -> out ----
    {
        f32x4 a0 = {0.f, 0.f, 0.f, 0.f}, a1 = {0.f, 0.f, 0.f, 0.f};
#pragma unroll
        for (int kt = 0; kt < 16; kt++) {
            const bf16x8 aP = *(const bf16x8*)&hb[(mt * 16 + l15) * 520 + kt * 32 + quad * 8];
            bf16x8 b0 = *(const bf16x8*)&wfc2[nR0 * 512 + kt * 32 + quad * 8];
            bf16x8 b1 = *(const bf16x8*)&wfc2[nR1 * 512 + kt * 32 + quad * 8];
            a0 = __builtin_amdgcn_mfma_f32_16x16x32_bf16(aP, b0, a0, 0, 0, 0);
            a1 = __builtin_amdgcn_mfma_f32_16x16x32_bf16(aP, b1, a1, 0, 0, 0);
        }
        const float b0s = fc2_b[nR0], b1s = fc2_b[nR1];
#pragma unroll
        for (int r = 0; r < 4; r++) {
            const int m = mt * 16 + quad * 4 + r;
            const int p = (i0 + (m >> 2)) * HW + j0 + (m & 3);
            out[(size_t)p * C + nR0] = a0[r] + b0s + bs2f(x1b[m * 136 + nR0]);
            out[(size_t)p * C + nR1] = a1[r] + b1s + bs2f(x1b[m * 136 + nR1]);
        }
    }
}

extern "C" void kernel_launch(void* const* d_in, const int* in_sizes, int n_in,
                              void* d_out, int out_size, void* d_ws, size_t ws_size,
                              hipStream_t stream) {
    const float* x      = (const float*)d_in[0];
    const float* y      = (const float*)d_in[1];
    const float* qv_w   = (const float*)d_in[2];
    const float* qv_b   = (const float*)d_in[3];
    const float* k_w    = (const float*)d_in[4];
    const float* k_b    = (const float*)d_in[5];
    const float* rpb    = (const float*)d_in[6];
    const float* proj_w = (const float*)d_in[7];
    const float* proj_b = (const float*)d_in[8];
    const float* n1_w   = (const float*)d_in[9];
    const float* n1_b   = (const float*)d_in[10];
    const float* n2_w   = (const float*)d_in[11];
    const float* n2_b   = (const float*)d_in[12];
    const float* fc1_w  = (const float*)d_in[13];
    const float* fc1_b  = (const float*)d_in[14];
    const float* fc2_w  = (const float*)d_in[15];
    const float* fc2_b  = (const float*)d_in[16];
    float* out = (float*)d_out;

    bf16* qb  = (bf16*)d_ws;
    bf16* vb  = qb + (size_t)N_PIX * C;
    bf16* kb  = vb + (size_t)N_PIX * C;
    bf16* xb  = kb + (size_t)N_PIX * C;             // bf16 copy of x (4 MB)
    short* wqv  = (short*)(xb + (size_t)N_PIX * C); // 32768
    short* wk   = wqv + 32768;                      // 16384
    short* wproj= wk + 16384;                       // 16384
    short* wfc1 = wproj + 16384;                    // 65536
    short* wfc2 = wfc1 + 65536;                     // 65536  (total ~16.4 MB)

    k_wconv<<<256, 256, 0, stream>>>(qv_w, k_w, proj_w, fc1_w, fc2_w,
                                     wqv, wk, wproj, wfc1, wfc2);
    k_qkv<<<512, 512, 0, stream>>>(x, y, wqv, qv_b, wk, k_b, n1_w, n1_b,
                                   qb, vb, kb, xb);
    k_fam<<<512, 512, 0, stream>>>(qb, kb, vb, rpb, xb, wproj, proj_b, n2_w, n2_b,
                                   wfc1, fc1_b, wfc2, fc2_b, out);
}